// Round 3
// baseline (4623.009 us; speedup 1.0000x reference)
//
#include <hip/hip_runtime.h>

#define N_USER 100000
#define N_ITEM 100000
#define NEDGE  500000
#define KDIM   128

// ---------------- GEMM: out[M][N] = act(A[M][128]) @ W[128][N] + b ----------------
// act = identity (lrelu=0) or leaky_relu slope 0.01 applied to A (lrelu=1)
template<int N>
__global__ __launch_bounds__(256)
void gemm_kernel(const float* __restrict__ A, const float* __restrict__ W,
                 const float* __restrict__ bias, float* __restrict__ out,
                 int M, int lrelu)
{
    constexpr int BM = 64, BK = 32, K = KDIM;
    constexpr int TM = 4;
    constexpr int TN = N / 16;            // 8 for N=128, 4 for N=64
    __shared__ float As[BM][BK + 4];      // row stride 36 floats (16B-aligned, conflict-benign)
    __shared__ float Ws[BK][N];

    const int tid = threadIdx.x;
    const int rowBase = blockIdx.x * BM;
    const int rg = tid >> 4;              // 0..15
    const int cg = tid & 15;              // 0..15
    const int r0 = rg * TM;
    const int c0 = cg * TN;

    float acc[TM][TN];
#pragma unroll
    for (int i = 0; i < TM; ++i)
#pragma unroll
        for (int j = 0; j < TN; ++j) acc[i][j] = 0.f;

    for (int kt = 0; kt < K / BK; ++kt) {
        // ---- load A tile (64 x 32), float4 per thread x2 ----
#pragma unroll
        for (int it = 0; it < (BM * BK / 4) / 256; ++it) {
            int l = tid + it * 256;
            int row = l >> 3;             // 8 float4-chunks per row
            int j4 = (l & 7) << 2;
            int gr = rowBase + row;
            float4 v = make_float4(0.f, 0.f, 0.f, 0.f);
            if (gr < M)
                v = *reinterpret_cast<const float4*>(&A[(size_t)gr * K + kt * BK + j4]);
            if (lrelu) {
                v.x = v.x > 0.f ? v.x : 0.01f * v.x;
                v.y = v.y > 0.f ? v.y : 0.01f * v.y;
                v.z = v.z > 0.f ? v.z : 0.01f * v.z;
                v.w = v.w > 0.f ? v.w : 0.01f * v.w;
            }
            *reinterpret_cast<float4*>(&As[row][j4]) = v;
        }
        // ---- load W tile (32 x N) ----
#pragma unroll
        for (int it = 0; it < (BK * N / 4) / 256; ++it) {
            int l = tid + it * 256;
            int kr = l / (N / 4);
            int c4 = (l % (N / 4)) << 2;
            float4 v = *reinterpret_cast<const float4*>(&W[(size_t)(kt * BK + kr) * N + c4]);
            *reinterpret_cast<float4*>(&Ws[kr][c4]) = v;
        }
        __syncthreads();

#pragma unroll
        for (int k = 0; k < BK; ++k) {
            float a[TM];
#pragma unroll
            for (int i = 0; i < TM; ++i) a[i] = As[r0 + i][k];
            float w[TN];
#pragma unroll
            for (int j = 0; j < TN; j += 4) {
                float4 wv = *reinterpret_cast<const float4*>(&Ws[k][c0 + j]);
                w[j + 0] = wv.x; w[j + 1] = wv.y; w[j + 2] = wv.z; w[j + 3] = wv.w;
            }
#pragma unroll
            for (int i = 0; i < TM; ++i)
#pragma unroll
                for (int j = 0; j < TN; ++j)
                    acc[i][j] = fmaf(a[i], w[j], acc[i][j]);
        }
        __syncthreads();
    }

    // ---- epilogue: + bias, store ----
#pragma unroll
    for (int i = 0; i < TM; ++i) {
        int gr = rowBase + r0 + i;
        if (gr < M) {
#pragma unroll
            for (int j = 0; j < TN; j += 4) {
                float4 v;
                v.x = acc[i][j + 0] + bias[c0 + j + 0];
                v.y = acc[i][j + 1] + bias[c0 + j + 1];
                v.z = acc[i][j + 2] + bias[c0 + j + 2];
                v.w = acc[i][j + 3] + bias[c0 + j + 3];
                *reinterpret_cast<float4*>(&out[(size_t)gr * N + c0 + j]) = v;
            }
        }
    }
}

// ---------------- degree count / inverse ----------------
__global__ void count_kernel(const int* __restrict__ dst, float* __restrict__ cnt, int E)
{
    int i = blockIdx.x * blockDim.x + threadIdx.x;
    if (i < E) atomicAdd(&cnt[dst[i]], 1.0f);
}

__global__ void inv_kernel(float* __restrict__ cnt, int n)
{
    int i = blockIdx.x * blockDim.x + threadIdx.x;
    if (i < n) cnt[i] = 1.0f / fmaxf(cnt[i], 1.0f);
}

// ---------------- scatter: acc[dst] += Wh[src] * inv[dst] ----------------
template<int D>
__global__ __launch_bounds__(256)
void scatter_kernel(const float* __restrict__ Wh, const int* __restrict__ src,
                    const int* __restrict__ dst, const float* __restrict__ inv,
                    float* __restrict__ acc, int E)
{
    constexpr int CH = D / 4;   // float4 chunks per row (32 or 16) -> power of 2
    int gid = blockIdx.x * blockDim.x + threadIdx.x;
    if (gid >= E * CH) return;
    int e  = gid / CH;
    int ch = gid % CH;
    int s = src[e];
    int d = dst[e];
    float sc = inv[d];
    float4 v = *reinterpret_cast<const float4*>(&Wh[(size_t)s * D + (ch << 2)]);
    float* p = &acc[(size_t)d * D + (ch << 2)];
    atomicAdd(p + 0, v.x * sc);
    atomicAdd(p + 1, v.y * sc);
    atomicAdd(p + 2, v.z * sc);
    atomicAdd(p + 3, v.w * sc);
}

extern "C" void kernel_launch(void* const* d_in, const int* in_sizes, int n_in,
                              void* d_out, int out_size, void* d_ws, size_t ws_size,
                              hipStream_t stream)
{
    const float* emb_user = (const float*)d_in[0];
    const float* emb_item = (const float*)d_in[1];
    // per etype: W1, b1, W2, b2
    const float* W1_rates    = (const float*)d_in[2];
    const float* b1_rates    = (const float*)d_in[3];
    const float* W2_rates    = (const float*)d_in[4];   (void)W2_rates;
    const float* b2_rates    = (const float*)d_in[5];   (void)b2_rates;
    const float* W1_rated_by = (const float*)d_in[6];
    const float* b1_rated_by = (const float*)d_in[7];
    const float* W2_rated_by = (const float*)d_in[8];
    const float* b2_rated_by = (const float*)d_in[9];
    const float* W1_follows  = (const float*)d_in[10];
    const float* b1_follows  = (const float*)d_in[11];
    const float* W2_follows  = (const float*)d_in[12];
    const float* b2_follows  = (const float*)d_in[13];
    const float* W1_similar  = (const float*)d_in[14];
    const float* b1_similar  = (const float*)d_in[15];
    const float* W2_similar  = (const float*)d_in[16];  (void)W2_similar;
    const float* b2_similar  = (const float*)d_in[17];  (void)b2_similar;
    const int* src_rates    = (const int*)d_in[18];
    const int* dst_rates    = (const int*)d_in[19];
    const int* src_rated_by = (const int*)d_in[20];
    const int* dst_rated_by = (const int*)d_in[21];
    const int* src_follows  = (const int*)d_in[22];
    const int* dst_follows  = (const int*)d_in[23];
    const int* src_similar  = (const int*)d_in[24];
    const int* dst_similar  = (const int*)d_in[25];

    float* out = (float*)d_out;

    // workspace layout (floats): Wh | acc_user | acc_item | cnt_rates | cnt_rated_by | cnt_follows | cnt_similar
    float* ws    = (float*)d_ws;
    float* Wh    = ws;
    float* acc_u = Wh    + (size_t)N_USER * 128;
    float* acc_i = acc_u + (size_t)N_USER * 128;
    float* cnt_r  = acc_i + (size_t)N_ITEM * 128;
    float* cnt_rb = cnt_r  + N_ITEM;
    float* cnt_f  = cnt_rb + N_USER;
    float* cnt_s  = cnt_f  + N_USER;

    hipMemsetAsync(acc_u, 0, (size_t)N_USER * 128 * sizeof(float), stream);
    hipMemsetAsync(acc_i, 0, (size_t)N_ITEM * 128 * sizeof(float), stream);
    hipMemsetAsync(cnt_r, 0, (size_t)(N_ITEM + N_USER + N_USER + N_ITEM) * sizeof(float), stream);
    hipMemsetAsync(out,   0, (size_t)out_size * sizeof(float), stream);

    const int eb = (NEDGE + 255) / 256;
    count_kernel<<<eb, 256, 0, stream>>>(dst_rates,    cnt_r,  NEDGE);
    count_kernel<<<eb, 256, 0, stream>>>(dst_rated_by, cnt_rb, NEDGE);
    count_kernel<<<eb, 256, 0, stream>>>(dst_follows,  cnt_f,  NEDGE);
    count_kernel<<<eb, 256, 0, stream>>>(dst_similar,  cnt_s,  NEDGE);
    inv_kernel<<<(4 * 100000 + 255) / 256, 256, 0, stream>>>(cnt_r, 4 * 100000);

    const int gb = (N_USER + 63) / 64;            // 1563 blocks (N_USER == N_ITEM)
    const int sb128 = (NEDGE * 32 + 255) / 256;   // 62500
    const int sb64  = (NEDGE * 16 + 255) / 256;   // 31250

    // ---------------- layer 1 ----------------
    // h_item: rates (user->item) + similar (item->item)
    gemm_kernel<128><<<gb, 256, 0, stream>>>(emb_user, W1_rates, b1_rates, Wh, N_USER, 0);
    scatter_kernel<128><<<sb128, 256, 0, stream>>>(Wh, src_rates, dst_rates, cnt_r, acc_i, NEDGE);
    gemm_kernel<128><<<gb, 256, 0, stream>>>(emb_item, W1_similar, b1_similar, Wh, N_ITEM, 0);
    scatter_kernel<128><<<sb128, 256, 0, stream>>>(Wh, src_similar, dst_similar, cnt_s, acc_i, NEDGE);
    // h_user: rated_by (item->user) + follows (user->user)
    gemm_kernel<128><<<gb, 256, 0, stream>>>(emb_item, W1_rated_by, b1_rated_by, Wh, N_ITEM, 0);
    scatter_kernel<128><<<sb128, 256, 0, stream>>>(Wh, src_rated_by, dst_rated_by, cnt_rb, acc_u, NEDGE);
    gemm_kernel<128><<<gb, 256, 0, stream>>>(emb_user, W1_follows, b1_follows, Wh, N_USER, 0);
    scatter_kernel<128><<<sb128, 256, 0, stream>>>(Wh, src_follows, dst_follows, cnt_f, acc_u, NEDGE);

    // ---------------- layer 2 (user output only) ----------------
    // leaky_relu fused into GEMM A-load. Only rated_by + follows reach users.
    gemm_kernel<64><<<gb, 256, 0, stream>>>(acc_i, W2_rated_by, b2_rated_by, Wh, N_ITEM, 1);
    scatter_kernel<64><<<sb64, 256, 0, stream>>>(Wh, src_rated_by, dst_rated_by, cnt_rb, out, NEDGE);
    gemm_kernel<64><<<gb, 256, 0, stream>>>(acc_u, W2_follows, b2_follows, Wh, N_USER, 1);
    scatter_kernel<64><<<sb64, 256, 0, stream>>>(Wh, src_follows, dst_follows, cnt_f, out, NEDGE);
}

// Round 4
// 831.555 us; speedup vs baseline: 5.5595x; 5.5595x over previous
//
#include <hip/hip_runtime.h>
#include <hip/hip_fp16.h>

#define N_USER 100000
#define N_ITEM 100000
#define NEDGE  500000
#define KDIM   128
#define NSEG   400000          // 4 relations x 100k dst nodes (concatenated count array)
#define SCAN_CHUNK 1024
#define NBLK   391             // ceil(NSEG / SCAN_CHUNK)

// ---------------- GEMM: out[M][N] = act(A[M][128]) @ W[128][N] + b, out is fp16 ----------------
template<int N>
__global__ __launch_bounds__(256)
void gemm_kernel(const float* __restrict__ A, const float* __restrict__ W,
                 const float* __restrict__ bias, __half* __restrict__ out,
                 int M, int lrelu)
{
    constexpr int BM = 64, BK = 32, K = KDIM;
    constexpr int TM = 4;
    constexpr int TN = N / 16;            // 8 for N=128, 4 for N=64
    __shared__ float As[BM][BK + 4];
    __shared__ float Ws[BK][N];

    const int tid = threadIdx.x;
    const int rowBase = blockIdx.x * BM;
    const int rg = tid >> 4;
    const int cg = tid & 15;
    const int r0 = rg * TM;
    const int c0 = cg * TN;

    float acc[TM][TN];
#pragma unroll
    for (int i = 0; i < TM; ++i)
#pragma unroll
        for (int j = 0; j < TN; ++j) acc[i][j] = 0.f;

    for (int kt = 0; kt < K / BK; ++kt) {
#pragma unroll
        for (int it = 0; it < (BM * BK / 4) / 256; ++it) {
            int l = tid + it * 256;
            int row = l >> 3;
            int j4 = (l & 7) << 2;
            int gr = rowBase + row;
            float4 v = make_float4(0.f, 0.f, 0.f, 0.f);
            if (gr < M)
                v = *reinterpret_cast<const float4*>(&A[(size_t)gr * K + kt * BK + j4]);
            if (lrelu) {
                v.x = v.x > 0.f ? v.x : 0.01f * v.x;
                v.y = v.y > 0.f ? v.y : 0.01f * v.y;
                v.z = v.z > 0.f ? v.z : 0.01f * v.z;
                v.w = v.w > 0.f ? v.w : 0.01f * v.w;
            }
            *reinterpret_cast<float4*>(&As[row][j4]) = v;
        }
#pragma unroll
        for (int it = 0; it < (BK * N / 4) / 256; ++it) {
            int l = tid + it * 256;
            int kr = l / (N / 4);
            int c4 = (l % (N / 4)) << 2;
            float4 v = *reinterpret_cast<const float4*>(&W[(size_t)(kt * BK + kr) * N + c4]);
            *reinterpret_cast<float4*>(&Ws[kr][c4]) = v;
        }
        __syncthreads();

#pragma unroll
        for (int k = 0; k < BK; ++k) {
            float a[TM];
#pragma unroll
            for (int i = 0; i < TM; ++i) a[i] = As[r0 + i][k];
            float w[TN];
#pragma unroll
            for (int j = 0; j < TN; j += 4) {
                float4 wv = *reinterpret_cast<const float4*>(&Ws[k][c0 + j]);
                w[j + 0] = wv.x; w[j + 1] = wv.y; w[j + 2] = wv.z; w[j + 3] = wv.w;
            }
#pragma unroll
            for (int i = 0; i < TM; ++i)
#pragma unroll
                for (int j = 0; j < TN; ++j)
                    acc[i][j] = fmaf(a[i], w[j], acc[i][j]);
        }
        __syncthreads();
    }

#pragma unroll
    for (int i = 0; i < TM; ++i) {
        int gr = rowBase + r0 + i;
        if (gr < M) {
            __half tmp[TN];
#pragma unroll
            for (int j = 0; j < TN; ++j)
                tmp[j] = __float2half(acc[i][j] + bias[c0 + j]);
            if (TN == 8)
                *reinterpret_cast<uint4*>(&out[(size_t)gr * N + c0]) =
                    *reinterpret_cast<const uint4*>(tmp);
            else
                *reinterpret_cast<uint2*>(&out[(size_t)gr * N + c0]) =
                    *reinterpret_cast<const uint2*>(tmp);
        }
    }
}

// ---------------- degree count (int) ----------------
__global__ void count_kernel(const int* __restrict__ dst, int* __restrict__ cnt,
                             int segBase, int E)
{
    int i = blockIdx.x * blockDim.x + threadIdx.x;
    if (i < E) atomicAdd(&cnt[segBase + dst[i]], 1);
}

// ---------------- 3-kernel exclusive scan over NSEG ints ----------------
__global__ __launch_bounds__(256)
void scan_a(const int* __restrict__ cnt, int* __restrict__ row_start, int* __restrict__ blkSums)
{
    __shared__ int sd[256];
    int t = threadIdx.x;
    int base = blockIdx.x * SCAN_CHUNK + t * 4;
    int v0 = 0, v1 = 0, v2 = 0, v3 = 0;
    if (base + 3 < NSEG) {
        int4 c = *reinterpret_cast<const int4*>(&cnt[base]);
        v0 = c.x; v1 = c.y; v2 = c.z; v3 = c.w;
    } else {
        if (base + 0 < NSEG) v0 = cnt[base + 0];
        if (base + 1 < NSEG) v1 = cnt[base + 1];
        if (base + 2 < NSEG) v2 = cnt[base + 2];
        if (base + 3 < NSEG) v3 = cnt[base + 3];
    }
    int T = v0 + v1 + v2 + v3;
    sd[t] = T; __syncthreads();
    for (int off = 1; off < 256; off <<= 1) {
        int u = (t >= off) ? sd[t - off] : 0;
        __syncthreads();
        sd[t] += u;
        __syncthreads();
    }
    int ex = sd[t] - T;
    if (base + 0 < NSEG) row_start[base + 0] = ex;
    if (base + 1 < NSEG) row_start[base + 1] = ex + v0;
    if (base + 2 < NSEG) row_start[base + 2] = ex + v0 + v1;
    if (base + 3 < NSEG) row_start[base + 3] = ex + v0 + v1 + v2;
    if (t == 255) blkSums[blockIdx.x] = sd[255];
}

__global__ __launch_bounds__(512)
void scan_b(int* blkSums)
{
    __shared__ int sd[512];
    int t = threadIdx.x;
    int v = (t < NBLK) ? blkSums[t] : 0;
    sd[t] = v; __syncthreads();
    for (int off = 1; off < 512; off <<= 1) {
        int u = (t >= off) ? sd[t - off] : 0;
        __syncthreads();
        sd[t] += u;
        __syncthreads();
    }
    if (t < NBLK) blkSums[t] = sd[t] - v;   // exclusive
}

__global__ __launch_bounds__(256)
void scan_c(int* __restrict__ row_start, int* __restrict__ cursor, const int* __restrict__ blkSums)
{
    int t = threadIdx.x;
    int base = blockIdx.x * SCAN_CHUNK + t * 4;
    int off = blkSums[blockIdx.x];
#pragma unroll
    for (int k = 0; k < 4; ++k) {
        int i = base + k;
        if (i < NSEG) {
            int r = row_start[i] + off;
            row_start[i] = r;
            cursor[i] = r;
        }
    }
    if (blockIdx.x == 0 && t == 0) row_start[NSEG] = 4 * NEDGE;
}

// ---------------- CSR bucket fill ----------------
__global__ void fill_kernel(const int* __restrict__ src, const int* __restrict__ dst,
                            int* __restrict__ cursor, int* __restrict__ csr_src,
                            int segBase, int E)
{
    int i = blockIdx.x * blockDim.x + threadIdx.x;
    if (i < E) {
        int pos = atomicAdd(&cursor[segBase + dst[i]], 1);
        csr_src[pos] = src[i];
    }
}

// ---------------- pull aggregation: one wave per dst row ----------------
// out[row] (ACCUM? += : =) mean_{e in row} Wh[csr_src[e]]
template<int D, bool ACCUM>
__global__ __launch_bounds__(256)
void pull_kernel(const __half* __restrict__ Wh, const int* __restrict__ row_start,
                 const int* __restrict__ csr_src, float* __restrict__ out,
                 int segBase, int nRows)
{
    int wid = (blockIdx.x * blockDim.x + threadIdx.x) >> 6;
    int lane = threadIdx.x & 63;
    if (wid >= nRows) return;
    int idx = segBase + wid;
    int start = row_start[idx];
    int end   = row_start[idx + 1];
    float inv = 1.0f / (float)max(end - start, 1);
    if (D == 128) {
        float2 acc = make_float2(0.f, 0.f);
        for (int e = start; e < end; ++e) {
            int s = csr_src[e];
            __half2 h = *reinterpret_cast<const __half2*>(&Wh[(size_t)s * 128 + lane * 2]);
            float2 f = __half22float2(h);
            acc.x += f.x; acc.y += f.y;
        }
        float2* p = reinterpret_cast<float2*>(&out[(size_t)wid * 128 + lane * 2]);
        if (ACCUM) {
            float2 cur = *p;
            cur.x += acc.x * inv; cur.y += acc.y * inv;
            *p = cur;
        } else {
            *p = make_float2(acc.x * inv, acc.y * inv);
        }
    } else {
        float acc = 0.f;
        for (int e = start; e < end; ++e) {
            int s = csr_src[e];
            acc += __half2float(Wh[(size_t)s * 64 + lane]);
        }
        float* p = &out[(size_t)wid * 64 + lane];
        if (ACCUM) *p += acc * inv;
        else       *p  = acc * inv;
    }
}

extern "C" void kernel_launch(void* const* d_in, const int* in_sizes, int n_in,
                              void* d_out, int out_size, void* d_ws, size_t ws_size,
                              hipStream_t stream)
{
    const float* emb_user = (const float*)d_in[0];
    const float* emb_item = (const float*)d_in[1];
    const float* W1_rates    = (const float*)d_in[2];
    const float* b1_rates    = (const float*)d_in[3];
    const float* W1_rated_by = (const float*)d_in[6];
    const float* b1_rated_by = (const float*)d_in[7];
    const float* W2_rated_by = (const float*)d_in[8];
    const float* b2_rated_by = (const float*)d_in[9];
    const float* W1_follows  = (const float*)d_in[10];
    const float* b1_follows  = (const float*)d_in[11];
    const float* W2_follows  = (const float*)d_in[12];
    const float* b2_follows  = (const float*)d_in[13];
    const float* W1_similar  = (const float*)d_in[14];
    const float* b1_similar  = (const float*)d_in[15];
    const int* src_rates    = (const int*)d_in[18];
    const int* dst_rates    = (const int*)d_in[19];
    const int* src_rated_by = (const int*)d_in[20];
    const int* dst_rated_by = (const int*)d_in[21];
    const int* src_follows  = (const int*)d_in[22];
    const int* dst_follows  = (const int*)d_in[23];
    const int* src_similar  = (const int*)d_in[24];
    const int* dst_similar  = (const int*)d_in[25];

    float* out = (float*)d_out;

    // ---- workspace layout ----
    // Wh (fp16, 100k x 128)            : 25,600,000 B
    // acc_i (f32, 100k x 128)          : 51,200,000 B
    // acc_u (f32, 100k x 128)          : 51,200,000 B
    // cnt[NSEG], row_start[NSEG+1], cursor[NSEG], blkSums[512], csr_src[2M]
    char* base = (char*)d_ws;
    __half* Wh   = (__half*)base;
    float* acc_i = (float*)(base + 25600000);
    float* acc_u = (float*)(base + 25600000 + 51200000);
    int* cnt       = (int*)(base + 25600000 + 2 * 51200000);
    int* row_start = cnt + NSEG;            // NSEG+1 entries
    int* cursor    = row_start + NSEG + 1;
    int* blkSums   = cursor + NSEG;
    int* csr_src   = blkSums + 512;

    // segment bases in the concatenated per-dst count array
    const int SEG_RATES = 0;               // dst = item
    const int SEG_RATED_BY = 100000;       // dst = user
    const int SEG_FOLLOWS = 200000;        // dst = user
    const int SEG_SIMILAR = 300000;        // dst = item

    hipMemsetAsync(cnt, 0, NSEG * sizeof(int), stream);

    const int eb = (NEDGE + 255) / 256;
    count_kernel<<<eb, 256, 0, stream>>>(dst_rates,    cnt, SEG_RATES,    NEDGE);
    count_kernel<<<eb, 256, 0, stream>>>(dst_rated_by, cnt, SEG_RATED_BY, NEDGE);
    count_kernel<<<eb, 256, 0, stream>>>(dst_follows,  cnt, SEG_FOLLOWS,  NEDGE);
    count_kernel<<<eb, 256, 0, stream>>>(dst_similar,  cnt, SEG_SIMILAR,  NEDGE);

    scan_a<<<NBLK, 256, 0, stream>>>(cnt, row_start, blkSums);
    scan_b<<<1, 512, 0, stream>>>(blkSums);
    scan_c<<<NBLK, 256, 0, stream>>>(row_start, cursor, blkSums);

    fill_kernel<<<eb, 256, 0, stream>>>(src_rates,    dst_rates,    cursor, csr_src, SEG_RATES,    NEDGE);
    fill_kernel<<<eb, 256, 0, stream>>>(src_rated_by, dst_rated_by, cursor, csr_src, SEG_RATED_BY, NEDGE);
    fill_kernel<<<eb, 256, 0, stream>>>(src_follows,  dst_follows,  cursor, csr_src, SEG_FOLLOWS,  NEDGE);
    fill_kernel<<<eb, 256, 0, stream>>>(src_similar,  dst_similar,  cursor, csr_src, SEG_SIMILAR,  NEDGE);

    const int gb = (100000 + 63) / 64;         // GEMM blocks (M=100k, BM=64)
    const int pb = (100000 * 64 + 255) / 256;  // pull blocks: 1 wave per row, 4 waves/block

    // ---------------- layer 1 ----------------
    // h_item = mean_rates(Wh(emb_user @ W1_rates)) + mean_similar(Wh(emb_item @ W1_similar))
    gemm_kernel<128><<<gb, 256, 0, stream>>>(emb_user, W1_rates, b1_rates, Wh, N_USER, 0);
    pull_kernel<128, false><<<pb, 256, 0, stream>>>(Wh, row_start, csr_src, acc_i, SEG_RATES, N_ITEM);
    gemm_kernel<128><<<gb, 256, 0, stream>>>(emb_item, W1_similar, b1_similar, Wh, N_ITEM, 0);
    pull_kernel<128, true><<<pb, 256, 0, stream>>>(Wh, row_start, csr_src, acc_i, SEG_SIMILAR, N_ITEM);
    // h_user = mean_rated_by(Wh(emb_item @ W1_rated_by)) + mean_follows(Wh(emb_user @ W1_follows))
    gemm_kernel<128><<<gb, 256, 0, stream>>>(emb_item, W1_rated_by, b1_rated_by, Wh, N_ITEM, 0);
    pull_kernel<128, false><<<pb, 256, 0, stream>>>(Wh, row_start, csr_src, acc_u, SEG_RATED_BY, N_USER);
    gemm_kernel<128><<<gb, 256, 0, stream>>>(emb_user, W1_follows, b1_follows, Wh, N_USER, 0);
    pull_kernel<128, true><<<pb, 256, 0, stream>>>(Wh, row_start, csr_src, acc_u, SEG_FOLLOWS, N_USER);

    // ---------------- layer 2 (user output only; leaky_relu fused into GEMM A-load) ----------------
    gemm_kernel<64><<<gb, 256, 0, stream>>>(acc_i, W2_rated_by, b2_rated_by, Wh, N_ITEM, 1);
    pull_kernel<64, false><<<pb, 256, 0, stream>>>(Wh, row_start, csr_src, out, SEG_RATED_BY, N_USER);
    gemm_kernel<64><<<gb, 256, 0, stream>>>(acc_u, W2_follows, b2_follows, Wh, N_USER, 1);
    pull_kernel<64, true><<<pb, 256, 0, stream>>>(Wh, row_start, csr_src, out, SEG_FOLLOWS, N_USER);
}

// Round 5
// 617.837 us; speedup vs baseline: 7.4826x; 1.3459x over previous
//
#include <hip/hip_runtime.h>
#include <hip/hip_fp16.h>

#define N_USER 100000
#define N_ITEM 100000
#define NEDGE  500000
#define KDIM   128
#define NSEG   400000          // 4 relations x 100k dst nodes
#define SCAN_CHUNK 1024
#define NBLK   391             // ceil(NSEG / SCAN_CHUNK)

typedef _Float16 f16x8 __attribute__((ext_vector_type(8)));
typedef float    f32x4 __attribute__((ext_vector_type(4)));

// ---------------- MFMA GEMM: out[M][N] = act(A[M][128]) @ W[128][N] + b, out fp16 ----
// A fp32 -> fp16 in registers; W^T staged in LDS fp16 (once); no K-loop barriers.
template<int N>
__global__ __launch_bounds__(256)
void gemm_mfma(const float* __restrict__ A, const float* __restrict__ W,
               const float* __restrict__ bias, __half* __restrict__ out,
               int M, int lrelu)
{
    constexpr int WT_LD = 136;                // halves; 272B row stride (16B-aligned, padded)
    __shared__ _Float16 Wt[N][WT_LD];

    const int tid = threadIdx.x;
    // stage W^T (fp16) into LDS
    for (int i = tid; i < 128 * N; i += 256) {
        int k = i / N, n = i % N;
        Wt[n][k] = (_Float16)W[i];
    }
    __syncthreads();

    const int wave = tid >> 6, lane = tid & 63;
    const int l16 = lane & 15;                // A-row / B-col within fragment
    const int lk  = lane >> 4;                // k-group (0..3), 8 halves each
    const int rowBase = blockIdx.x * 128 + wave * 32;

    f32x4 acc[2][N / 16];
#pragma unroll
    for (int m = 0; m < 2; ++m)
#pragma unroll
        for (int n = 0; n < N / 16; ++n)
            acc[m][n] = (f32x4)0.f;

#pragma unroll
    for (int kt = 0; kt < 4; ++kt) {          // K = 128 in chunks of 32
        f16x8 afrag[2];
#pragma unroll
        for (int m = 0; m < 2; ++m) {
            int gr = rowBase + m * 16 + l16;
            float4 v0 = make_float4(0.f, 0.f, 0.f, 0.f);
            float4 v1 = v0;
            if (gr < M) {
                const float* p = &A[(size_t)gr * 128 + kt * 32 + lk * 8];
                v0 = *reinterpret_cast<const float4*>(p);
                v1 = *reinterpret_cast<const float4*>(p + 4);
            }
            if (lrelu) {
                v0.x = v0.x > 0.f ? v0.x : 0.01f * v0.x;
                v0.y = v0.y > 0.f ? v0.y : 0.01f * v0.y;
                v0.z = v0.z > 0.f ? v0.z : 0.01f * v0.z;
                v0.w = v0.w > 0.f ? v0.w : 0.01f * v0.w;
                v1.x = v1.x > 0.f ? v1.x : 0.01f * v1.x;
                v1.y = v1.y > 0.f ? v1.y : 0.01f * v1.y;
                v1.z = v1.z > 0.f ? v1.z : 0.01f * v1.z;
                v1.w = v1.w > 0.f ? v1.w : 0.01f * v1.w;
            }
            f16x8 a;
            a[0] = (_Float16)v0.x; a[1] = (_Float16)v0.y;
            a[2] = (_Float16)v0.z; a[3] = (_Float16)v0.w;
            a[4] = (_Float16)v1.x; a[5] = (_Float16)v1.y;
            a[6] = (_Float16)v1.z; a[7] = (_Float16)v1.w;
            afrag[m] = a;
        }
#pragma unroll
        for (int n = 0; n < N / 16; ++n) {
            f16x8 b = *reinterpret_cast<const f16x8*>(&Wt[n * 16 + l16][kt * 32 + lk * 8]);
            acc[0][n] = __builtin_amdgcn_mfma_f32_16x16x32_f16(afrag[0], b, acc[0][n], 0, 0, 0);
            acc[1][n] = __builtin_amdgcn_mfma_f32_16x16x32_f16(afrag[1], b, acc[1][n], 0, 0, 0);
        }
    }

    // epilogue: D[row=(lane>>4)*4+reg][col=lane&15]
#pragma unroll
    for (int m = 0; m < 2; ++m) {
        int gr0 = rowBase + m * 16 + lk * 4;
#pragma unroll
        for (int n = 0; n < N / 16; ++n) {
            float bv = bias[n * 16 + l16];
#pragma unroll
            for (int r = 0; r < 4; ++r) {
                int gr = gr0 + r;
                if (gr < M)
                    out[(size_t)gr * N + n * 16 + l16] = __float2half(acc[m][n][r] + bv);
            }
        }
    }
}

// ---------------- degree count: all 4 relations, rel = blockIdx.y ----------------
__global__ void count_all(const int* __restrict__ d0, const int* __restrict__ d1,
                          const int* __restrict__ d2, const int* __restrict__ d3,
                          int* __restrict__ cnt)
{
    int i = blockIdx.x * blockDim.x + threadIdx.x;
    if (i >= NEDGE) return;
    int rel = blockIdx.y;
    const int* d = rel == 0 ? d0 : rel == 1 ? d1 : rel == 2 ? d2 : d3;
    atomicAdd(&cnt[rel * 100000 + d[i]], 1);
}

// ---------------- 3-kernel exclusive scan over NSEG ints ----------------
__global__ __launch_bounds__(256)
void scan_a(const int* __restrict__ cnt, int* __restrict__ row_start, int* __restrict__ blkSums)
{
    __shared__ int sd[256];
    int t = threadIdx.x;
    int base = blockIdx.x * SCAN_CHUNK + t * 4;
    int v0 = 0, v1 = 0, v2 = 0, v3 = 0;
    if (base + 3 < NSEG) {
        int4 c = *reinterpret_cast<const int4*>(&cnt[base]);
        v0 = c.x; v1 = c.y; v2 = c.z; v3 = c.w;
    } else {
        if (base + 0 < NSEG) v0 = cnt[base + 0];
        if (base + 1 < NSEG) v1 = cnt[base + 1];
        if (base + 2 < NSEG) v2 = cnt[base + 2];
        if (base + 3 < NSEG) v3 = cnt[base + 3];
    }
    int T = v0 + v1 + v2 + v3;
    sd[t] = T; __syncthreads();
    for (int off = 1; off < 256; off <<= 1) {
        int u = (t >= off) ? sd[t - off] : 0;
        __syncthreads();
        sd[t] += u;
        __syncthreads();
    }
    int ex = sd[t] - T;
    if (base + 0 < NSEG) row_start[base + 0] = ex;
    if (base + 1 < NSEG) row_start[base + 1] = ex + v0;
    if (base + 2 < NSEG) row_start[base + 2] = ex + v0 + v1;
    if (base + 3 < NSEG) row_start[base + 3] = ex + v0 + v1 + v2;
    if (t == 255) blkSums[blockIdx.x] = sd[255];
}

__global__ __launch_bounds__(512)
void scan_b(int* blkSums)
{
    __shared__ int sd[512];
    int t = threadIdx.x;
    int v = (t < NBLK) ? blkSums[t] : 0;
    sd[t] = v; __syncthreads();
    for (int off = 1; off < 512; off <<= 1) {
        int u = (t >= off) ? sd[t - off] : 0;
        __syncthreads();
        sd[t] += u;
        __syncthreads();
    }
    if (t < NBLK) blkSums[t] = sd[t] - v;   // exclusive
}

__global__ __launch_bounds__(256)
void scan_c(int* __restrict__ row_start, int* __restrict__ cursor, const int* __restrict__ blkSums)
{
    int t = threadIdx.x;
    int base = blockIdx.x * SCAN_CHUNK + t * 4;
    int off = blkSums[blockIdx.x];
#pragma unroll
    for (int k = 0; k < 4; ++k) {
        int i = base + k;
        if (i < NSEG) {
            int r = row_start[i] + off;
            row_start[i] = r;
            cursor[i] = r;
        }
    }
    if (blockIdx.x == 0 && t == 0) row_start[NSEG] = 4 * NEDGE;
}

// ---------------- CSR bucket fill: all 4 relations ----------------
__global__ void fill_all(const int* __restrict__ s0, const int* __restrict__ d0,
                         const int* __restrict__ s1, const int* __restrict__ d1,
                         const int* __restrict__ s2, const int* __restrict__ d2,
                         const int* __restrict__ s3, const int* __restrict__ d3,
                         int* __restrict__ cursor, int* __restrict__ csr_src)
{
    int i = blockIdx.x * blockDim.x + threadIdx.x;
    if (i >= NEDGE) return;
    int rel = blockIdx.y;
    const int* s = rel == 0 ? s0 : rel == 1 ? s1 : rel == 2 ? s2 : s3;
    const int* d = rel == 0 ? d0 : rel == 1 ? d1 : rel == 2 ? d2 : d3;
    int pos = atomicAdd(&cursor[rel * 100000 + d[i]], 1);
    csr_src[pos] = s[i];
}

// ---------------- pull v2: one wave per dst row, 2 edges per half-wave pair ----------------
// out[row] (ACCUM? += : =) mean_{e in row} Wh[csr_src[e]]
template<int D, bool ACCUM>
__global__ __launch_bounds__(256)
void pull_kernel(const __half* __restrict__ Wh, const int* __restrict__ row_start,
                 const int* __restrict__ csr_src, float* __restrict__ out,
                 int segBase, int nRows)
{
    int wid = (blockIdx.x * blockDim.x + threadIdx.x) >> 6;
    int lane = threadIdx.x & 63;
    if (wid >= nRows) return;
    int idx = segBase + wid;
    int start = row_start[idx];
    int end   = row_start[idx + 1];
    float inv = 1.0f / (float)max(end - start, 1);
    int sub = lane >> 5;       // which edge of a pair
    int sl  = lane & 31;

    if (D == 128) {
        // lane covers 4 halves (8B) at dims sl*4; half-wave covers a 256B row
        float4 acc = make_float4(0.f, 0.f, 0.f, 0.f);
        int e = start;
        for (; e + 4 <= end; e += 4) {
            int sA = csr_src[e + sub];
            int sB = csr_src[e + 2 + sub];
            uint2 uA = *reinterpret_cast<const uint2*>(&Wh[(size_t)sA * 128 + sl * 4]);
            uint2 uB = *reinterpret_cast<const uint2*>(&Wh[(size_t)sB * 128 + sl * 4]);
            __half2 a0 = *reinterpret_cast<__half2*>(&uA.x);
            __half2 a1 = *reinterpret_cast<__half2*>(&uA.y);
            __half2 b0 = *reinterpret_cast<__half2*>(&uB.x);
            __half2 b1 = *reinterpret_cast<__half2*>(&uB.y);
            float2 fa0 = __half22float2(a0), fa1 = __half22float2(a1);
            float2 fb0 = __half22float2(b0), fb1 = __half22float2(b1);
            acc.x += fa0.x + fb0.x; acc.y += fa0.y + fb0.y;
            acc.z += fa1.x + fb1.x; acc.w += fa1.y + fb1.y;
        }
        if (e + 2 <= end) {
            int s = csr_src[e + sub];
            uint2 u = *reinterpret_cast<const uint2*>(&Wh[(size_t)s * 128 + sl * 4]);
            __half2 a0 = *reinterpret_cast<__half2*>(&u.x);
            __half2 a1 = *reinterpret_cast<__half2*>(&u.y);
            float2 f0 = __half22float2(a0), f1 = __half22float2(a1);
            acc.x += f0.x; acc.y += f0.y; acc.z += f1.x; acc.w += f1.y;
            e += 2;
        }
        if (e < end && sub == 0) {
            int s = csr_src[e];
            uint2 u = *reinterpret_cast<const uint2*>(&Wh[(size_t)s * 128 + sl * 4]);
            __half2 a0 = *reinterpret_cast<__half2*>(&u.x);
            __half2 a1 = *reinterpret_cast<__half2*>(&u.y);
            float2 f0 = __half22float2(a0), f1 = __half22float2(a1);
            acc.x += f0.x; acc.y += f0.y; acc.z += f1.x; acc.w += f1.y;
        }
        acc.x += __shfl_xor(acc.x, 32);
        acc.y += __shfl_xor(acc.y, 32);
        acc.z += __shfl_xor(acc.z, 32);
        acc.w += __shfl_xor(acc.w, 32);
        if (sub == 0) {
            float4* p = reinterpret_cast<float4*>(&out[(size_t)wid * 128 + sl * 4]);
            if (ACCUM) {
                float4 c = *p;
                c.x += acc.x * inv; c.y += acc.y * inv;
                c.z += acc.z * inv; c.w += acc.w * inv;
                *p = c;
            } else {
                *p = make_float4(acc.x * inv, acc.y * inv, acc.z * inv, acc.w * inv);
            }
        }
    } else {
        // D == 64: lane covers 2 halves (4B) at dims sl*2; half-wave covers a 128B row
        float2 acc = make_float2(0.f, 0.f);
        int e = start;
        for (; e + 4 <= end; e += 4) {
            int sA = csr_src[e + sub];
            int sB = csr_src[e + 2 + sub];
            __half2 hA = *reinterpret_cast<const __half2*>(&Wh[(size_t)sA * 64 + sl * 2]);
            __half2 hB = *reinterpret_cast<const __half2*>(&Wh[(size_t)sB * 64 + sl * 2]);
            float2 fA = __half22float2(hA), fB = __half22float2(hB);
            acc.x += fA.x + fB.x; acc.y += fA.y + fB.y;
        }
        if (e + 2 <= end) {
            int s = csr_src[e + sub];
            float2 f = __half22float2(*reinterpret_cast<const __half2*>(&Wh[(size_t)s * 64 + sl * 2]));
            acc.x += f.x; acc.y += f.y;
            e += 2;
        }
        if (e < end && sub == 0) {
            int s = csr_src[e];
            float2 f = __half22float2(*reinterpret_cast<const __half2*>(&Wh[(size_t)s * 64 + sl * 2]));
            acc.x += f.x; acc.y += f.y;
        }
        acc.x += __shfl_xor(acc.x, 32);
        acc.y += __shfl_xor(acc.y, 32);
        if (sub == 0) {
            float2* p = reinterpret_cast<float2*>(&out[(size_t)wid * 64 + sl * 2]);
            if (ACCUM) {
                float2 c = *p;
                c.x += acc.x * inv; c.y += acc.y * inv;
                *p = c;
            } else {
                *p = make_float2(acc.x * inv, acc.y * inv);
            }
        }
    }
}

extern "C" void kernel_launch(void* const* d_in, const int* in_sizes, int n_in,
                              void* d_out, int out_size, void* d_ws, size_t ws_size,
                              hipStream_t stream)
{
    const float* emb_user = (const float*)d_in[0];
    const float* emb_item = (const float*)d_in[1];
    const float* W1_rates    = (const float*)d_in[2];
    const float* b1_rates    = (const float*)d_in[3];
    const float* W1_rated_by = (const float*)d_in[6];
    const float* b1_rated_by = (const float*)d_in[7];
    const float* W2_rated_by = (const float*)d_in[8];
    const float* b2_rated_by = (const float*)d_in[9];
    const float* W1_follows  = (const float*)d_in[10];
    const float* b1_follows  = (const float*)d_in[11];
    const float* W2_follows  = (const float*)d_in[12];
    const float* b2_follows  = (const float*)d_in[13];
    const float* W1_similar  = (const float*)d_in[14];
    const float* b1_similar  = (const float*)d_in[15];
    const int* src_rates    = (const int*)d_in[18];
    const int* dst_rates    = (const int*)d_in[19];
    const int* src_rated_by = (const int*)d_in[20];
    const int* dst_rated_by = (const int*)d_in[21];
    const int* src_follows  = (const int*)d_in[22];
    const int* dst_follows  = (const int*)d_in[23];
    const int* src_similar  = (const int*)d_in[24];
    const int* dst_similar  = (const int*)d_in[25];

    float* out = (float*)d_out;

    // ---- workspace layout ----
    char* base = (char*)d_ws;
    __half* Wh   = (__half*)base;                              // 25.6 MB
    float* acc_i = (float*)(base + 25600000);                  // 51.2 MB
    float* acc_u = (float*)(base + 25600000 + 51200000);       // 51.2 MB
    int* cnt       = (int*)(base + 25600000 + 2 * 51200000);
    int* row_start = cnt + NSEG;            // NSEG+1 entries
    int* cursor    = row_start + NSEG + 1;
    int* blkSums   = cursor + NSEG;
    int* csr_src   = blkSums + 512;         // 2M entries

    const int SEG_RATES    = 0;             // dst = item
    const int SEG_RATED_BY = 100000;        // dst = user
    const int SEG_FOLLOWS  = 200000;        // dst = user
    const int SEG_SIMILAR  = 300000;        // dst = item

    hipMemsetAsync(cnt, 0, NSEG * sizeof(int), stream);

    const int eb = (NEDGE + 255) / 256;
    count_all<<<dim3(eb, 4), 256, 0, stream>>>(dst_rates, dst_rated_by, dst_follows, dst_similar, cnt);
    scan_a<<<NBLK, 256, 0, stream>>>(cnt, row_start, blkSums);
    scan_b<<<1, 512, 0, stream>>>(blkSums);
    scan_c<<<NBLK, 256, 0, stream>>>(row_start, cursor, blkSums);
    fill_all<<<dim3(eb, 4), 256, 0, stream>>>(src_rates, dst_rates, src_rated_by, dst_rated_by,
                                              src_follows, dst_follows, src_similar, dst_similar,
                                              cursor, csr_src);

    const int gb = (100000 + 127) / 128;       // MFMA GEMM blocks (BM=128)
    const int pb = (100000 * 64 + 255) / 256;  // pull: 1 wave/row, 4 waves/block

    // ---------------- layer 1 ----------------
    gemm_mfma<128><<<gb, 256, 0, stream>>>(emb_user, W1_rates, b1_rates, Wh, N_USER, 0);
    pull_kernel<128, false><<<pb, 256, 0, stream>>>(Wh, row_start, csr_src, acc_i, SEG_RATES, N_ITEM);
    gemm_mfma<128><<<gb, 256, 0, stream>>>(emb_item, W1_similar, b1_similar, Wh, N_ITEM, 0);
    pull_kernel<128, true><<<pb, 256, 0, stream>>>(Wh, row_start, csr_src, acc_i, SEG_SIMILAR, N_ITEM);
    gemm_mfma<128><<<gb, 256, 0, stream>>>(emb_item, W1_rated_by, b1_rated_by, Wh, N_ITEM, 0);
    pull_kernel<128, false><<<pb, 256, 0, stream>>>(Wh, row_start, csr_src, acc_u, SEG_RATED_BY, N_USER);
    gemm_mfma<128><<<gb, 256, 0, stream>>>(emb_user, W1_follows, b1_follows, Wh, N_USER, 0);
    pull_kernel<128, true><<<pb, 256, 0, stream>>>(Wh, row_start, csr_src, acc_u, SEG_FOLLOWS, N_USER);

    // ---------------- layer 2 (user output only; leaky_relu fused into GEMM A-load) ----------------
    gemm_mfma<64><<<gb, 256, 0, stream>>>(acc_i, W2_rated_by, b2_rated_by, Wh, N_ITEM, 1);
    pull_kernel<64, false><<<pb, 256, 0, stream>>>(Wh, row_start, csr_src, out, SEG_RATED_BY, N_USER);
    gemm_mfma<64><<<gb, 256, 0, stream>>>(acc_u, W2_follows, b2_follows, Wh, N_USER, 1);
    pull_kernel<64, true><<<pb, 256, 0, stream>>>(Wh, row_start, csr_src, out, SEG_FOLLOWS, N_USER);
}

// Round 6
// 436.440 us; speedup vs baseline: 10.5926x; 1.4156x over previous
//
#include <hip/hip_runtime.h>
#include <hip/hip_fp16.h>

#define N_USER 100000
#define N_ITEM 100000
#define NEDGE  500000
#define KDIM   128
#define NKEY   400000          // 4 relations x 100k dst nodes
#define BSHIFT 11              // 2048 keys per bucket
#define NB     196             // ceil(NKEY / 2048)
#define BCAP   11264           // pairs per bucket (mean 10240, sigma~101 -> +10 sigma)
#define TILE   4096

typedef _Float16 f16x8 __attribute__((ext_vector_type(8)));
typedef float    f32x4 __attribute__((ext_vector_type(4)));

// ---------------- MFMA GEMM: out[M][N] = act(A[M][128]) @ W[128][N] + b, out fp16 ----
template<int N>
__global__ __launch_bounds__(256)
void gemm_mfma(const float* __restrict__ A, const float* __restrict__ W,
               const float* __restrict__ bias, __half* __restrict__ out,
               int M, int lrelu)
{
    constexpr int WT_LD = 136;
    __shared__ _Float16 Wt[N][WT_LD];

    const int tid = threadIdx.x;
    for (int i = tid; i < 128 * N; i += 256) {
        int k = i / N, n = i % N;
        Wt[n][k] = (_Float16)W[i];
    }
    __syncthreads();

    const int wave = tid >> 6, lane = tid & 63;
    const int l16 = lane & 15;
    const int lk  = lane >> 4;
    const int rowBase = blockIdx.x * 128 + wave * 32;

    f32x4 acc[2][N / 16];
#pragma unroll
    for (int m = 0; m < 2; ++m)
#pragma unroll
        for (int n = 0; n < N / 16; ++n)
            acc[m][n] = (f32x4)0.f;

#pragma unroll
    for (int kt = 0; kt < 4; ++kt) {
        f16x8 afrag[2];
#pragma unroll
        for (int m = 0; m < 2; ++m) {
            int gr = rowBase + m * 16 + l16;
            float4 v0 = make_float4(0.f, 0.f, 0.f, 0.f);
            float4 v1 = v0;
            if (gr < M) {
                const float* p = &A[(size_t)gr * 128 + kt * 32 + lk * 8];
                v0 = *reinterpret_cast<const float4*>(p);
                v1 = *reinterpret_cast<const float4*>(p + 4);
            }
            if (lrelu) {
                v0.x = v0.x > 0.f ? v0.x : 0.01f * v0.x;
                v0.y = v0.y > 0.f ? v0.y : 0.01f * v0.y;
                v0.z = v0.z > 0.f ? v0.z : 0.01f * v0.z;
                v0.w = v0.w > 0.f ? v0.w : 0.01f * v0.w;
                v1.x = v1.x > 0.f ? v1.x : 0.01f * v1.x;
                v1.y = v1.y > 0.f ? v1.y : 0.01f * v1.y;
                v1.z = v1.z > 0.f ? v1.z : 0.01f * v1.z;
                v1.w = v1.w > 0.f ? v1.w : 0.01f * v1.w;
            }
            f16x8 a;
            a[0] = (_Float16)v0.x; a[1] = (_Float16)v0.y;
            a[2] = (_Float16)v0.z; a[3] = (_Float16)v0.w;
            a[4] = (_Float16)v1.x; a[5] = (_Float16)v1.y;
            a[6] = (_Float16)v1.z; a[7] = (_Float16)v1.w;
            afrag[m] = a;
        }
#pragma unroll
        for (int n = 0; n < N / 16; ++n) {
            f16x8 b = *reinterpret_cast<const f16x8*>(&Wt[n * 16 + l16][kt * 32 + lk * 8]);
            acc[0][n] = __builtin_amdgcn_mfma_f32_16x16x32_f16(afrag[0], b, acc[0][n], 0, 0, 0);
            acc[1][n] = __builtin_amdgcn_mfma_f32_16x16x32_f16(afrag[1], b, acc[1][n], 0, 0, 0);
        }
    }

#pragma unroll
    for (int m = 0; m < 2; ++m) {
        int gr0 = rowBase + m * 16 + lk * 4;
#pragma unroll
        for (int n = 0; n < N / 16; ++n) {
            float bv = bias[n * 16 + l16];
#pragma unroll
            for (int r = 0; r < 4; ++r) {
                int gr = gr0 + r;
                if (gr < M)
                    out[(size_t)gr * N + n * 16 + l16] = __float2half(acc[m][n][r] + bv);
            }
        }
    }
}

// ---------------- pass 1: partition edges into 196 buckets of (key,src) pairs ----------------
__global__ __launch_bounds__(256)
void partition_kernel(const int* __restrict__ s0, const int* __restrict__ d0,
                      const int* __restrict__ s1, const int* __restrict__ d1,
                      const int* __restrict__ s2, const int* __restrict__ d2,
                      const int* __restrict__ s3, const int* __restrict__ d3,
                      int* __restrict__ bucket_cursor, uint2* __restrict__ pairbuf)
{
    __shared__ int cntS[256], lscan[256], gbase[256], cur[256];
    __shared__ uint2 stage[TILE];
    __shared__ unsigned char bslot[TILE];

    const int t = threadIdx.x;
    const int rel = blockIdx.y;
    const int* S = rel == 0 ? s0 : rel == 1 ? s1 : rel == 2 ? s2 : s3;
    const int* D = rel == 0 ? d0 : rel == 1 ? d1 : rel == 2 ? d2 : d3;
    const int tileBase = blockIdx.x * TILE;
    const int tileN = min(TILE, NEDGE - tileBase);

    cntS[t] = 0;
    __syncthreads();

    int key[16], sv[16];
#pragma unroll
    for (int k = 0; k < 16; ++k) {
        int i = tileBase + k * 256 + t;
        if (i < NEDGE) {
            sv[k]  = S[i];
            key[k] = rel * 100000 + D[i];
            atomicAdd(&cntS[key[k] >> BSHIFT], 1);
        } else key[k] = -1;
    }
    __syncthreads();

    const int c = cntS[t];
    lscan[t] = c;
    __syncthreads();
    for (int off = 1; off < 256; off <<= 1) {
        int v = (t >= off) ? lscan[t - off] : 0;
        __syncthreads();
        lscan[t] += v;
        __syncthreads();
    }
    const int ex = lscan[t] - c;
    __syncthreads();
    lscan[t] = ex;
    cur[t]   = ex;
    if (t < NB && c > 0) gbase[t] = atomicAdd(&bucket_cursor[t], c);
    __syncthreads();

#pragma unroll
    for (int k = 0; k < 16; ++k) {
        if (key[k] >= 0) {
            int b = key[k] >> BSHIFT;
            int slot = atomicAdd(&cur[b], 1);
            stage[slot] = make_uint2((unsigned)key[k], (unsigned)sv[k]);
            bslot[slot] = (unsigned char)b;
        }
    }
    __syncthreads();

    for (int j = t; j < tileN; j += 256) {
        int b = bslot[j];
        pairbuf[(size_t)b * BCAP + gbase[b] + (j - lscan[b])] = stage[j];
    }
}

// ---------------- tiny scan of bucket totals ----------------
__global__ __launch_bounds__(256)
void bucket_scan(const int* __restrict__ bucket_cursor, int* __restrict__ gstart,
                 int* __restrict__ row_start)
{
    __shared__ int sd[256];
    int t = threadIdx.x;
    int v = (t < NB) ? bucket_cursor[t] : 0;
    sd[t] = v;
    __syncthreads();
    for (int off = 1; off < 256; off <<= 1) {
        int u = (t >= off) ? sd[t - off] : 0;
        __syncthreads();
        sd[t] += u;
        __syncthreads();
    }
    if (t < NB) gstart[t] = sd[t] - v;        // exclusive
    if (t == NB) gstart[NB] = sd[NB - 1];
    if (t == 0)  row_start[NKEY] = 4 * NEDGE;
}

// ---------------- pass 2: per-bucket bin sort -> row_start + csr_src ----------------
__global__ __launch_bounds__(256)
void build_csr(const uint2* __restrict__ pairbuf, const int* __restrict__ bucket_cursor,
               const int* __restrict__ gstart, int* __restrict__ row_start,
               int* __restrict__ csr_src)
{
    __shared__ int hist[2048];
    __shared__ int scan2[2048];
    __shared__ int partial[256];

    const int b = blockIdx.x;
    const int t = threadIdx.x;
    const int cnt = bucket_cursor[b];
    const int gs  = gstart[b];
    const uint2* pb = pairbuf + (size_t)b * BCAP;
    const int keyBase = b << BSHIFT;
    const int nbin = min(2048, NKEY - keyBase);

    for (int k = t; k < 2048; k += 256) hist[k] = 0;
    __syncthreads();
    for (int j = t; j < cnt; j += 256)
        atomicAdd(&hist[(int)pb[j].x - keyBase], 1);
    __syncthreads();

    const int base8 = t * 8;
    int s = 0;
#pragma unroll
    for (int k = 0; k < 8; ++k) s += hist[base8 + k];
    partial[t] = s;
    __syncthreads();
    for (int off = 1; off < 256; off <<= 1) {
        int u = (t >= off) ? partial[t - off] : 0;
        __syncthreads();
        partial[t] += u;
        __syncthreads();
    }
    int run = partial[t] - s;
#pragma unroll
    for (int k = 0; k < 8; ++k) { scan2[base8 + k] = run; run += hist[base8 + k]; }
    __syncthreads();

    for (int k = t; k < nbin; k += 256) row_start[keyBase + k] = gs + scan2[k];
    for (int k = t; k < 2048; k += 256) hist[k] = scan2[k];
    __syncthreads();

    for (int j = t; j < cnt; j += 256) {
        uint2 p = pb[j];
        int pos = atomicAdd(&hist[(int)p.x - keyBase], 1);
        csr_src[gs + pos] = (int)p.y;
    }
}

// ---------------- pull: one wave per dst row, 2 edges per half-wave pair ----------------
template<int D, bool ACCUM>
__global__ __launch_bounds__(256)
void pull_kernel(const __half* __restrict__ Wh, const int* __restrict__ row_start,
                 const int* __restrict__ csr_src, float* __restrict__ out,
                 int segBase, int nRows)
{
    int wid = (blockIdx.x * blockDim.x + threadIdx.x) >> 6;
    int lane = threadIdx.x & 63;
    if (wid >= nRows) return;
    int idx = segBase + wid;
    int start = row_start[idx];
    int end   = row_start[idx + 1];
    float inv = 1.0f / (float)max(end - start, 1);
    int sub = lane >> 5;
    int sl  = lane & 31;

    if (D == 128) {
        float4 acc = make_float4(0.f, 0.f, 0.f, 0.f);
        int e = start;
        for (; e + 4 <= end; e += 4) {
            int sA = csr_src[e + sub];
            int sB = csr_src[e + 2 + sub];
            uint2 uA = *reinterpret_cast<const uint2*>(&Wh[(size_t)sA * 128 + sl * 4]);
            uint2 uB = *reinterpret_cast<const uint2*>(&Wh[(size_t)sB * 128 + sl * 4]);
            __half2 a0 = *reinterpret_cast<__half2*>(&uA.x);
            __half2 a1 = *reinterpret_cast<__half2*>(&uA.y);
            __half2 b0 = *reinterpret_cast<__half2*>(&uB.x);
            __half2 b1 = *reinterpret_cast<__half2*>(&uB.y);
            float2 fa0 = __half22float2(a0), fa1 = __half22float2(a1);
            float2 fb0 = __half22float2(b0), fb1 = __half22float2(b1);
            acc.x += fa0.x + fb0.x; acc.y += fa0.y + fb0.y;
            acc.z += fa1.x + fb1.x; acc.w += fa1.y + fb1.y;
        }
        if (e + 2 <= end) {
            int s = csr_src[e + sub];
            uint2 u = *reinterpret_cast<const uint2*>(&Wh[(size_t)s * 128 + sl * 4]);
            __half2 a0 = *reinterpret_cast<__half2*>(&u.x);
            __half2 a1 = *reinterpret_cast<__half2*>(&u.y);
            float2 f0 = __half22float2(a0), f1 = __half22float2(a1);
            acc.x += f0.x; acc.y += f0.y; acc.z += f1.x; acc.w += f1.y;
            e += 2;
        }
        if (e < end && sub == 0) {
            int s = csr_src[e];
            uint2 u = *reinterpret_cast<const uint2*>(&Wh[(size_t)s * 128 + sl * 4]);
            __half2 a0 = *reinterpret_cast<__half2*>(&u.x);
            __half2 a1 = *reinterpret_cast<__half2*>(&u.y);
            float2 f0 = __half22float2(a0), f1 = __half22float2(a1);
            acc.x += f0.x; acc.y += f0.y; acc.z += f1.x; acc.w += f1.y;
        }
        acc.x += __shfl_xor(acc.x, 32);
        acc.y += __shfl_xor(acc.y, 32);
        acc.z += __shfl_xor(acc.z, 32);
        acc.w += __shfl_xor(acc.w, 32);
        if (sub == 0) {
            float4* p = reinterpret_cast<float4*>(&out[(size_t)wid * 128 + sl * 4]);
            if (ACCUM) {
                float4 c = *p;
                c.x += acc.x * inv; c.y += acc.y * inv;
                c.z += acc.z * inv; c.w += acc.w * inv;
                *p = c;
            } else {
                *p = make_float4(acc.x * inv, acc.y * inv, acc.z * inv, acc.w * inv);
            }
        }
    } else {
        float2 acc = make_float2(0.f, 0.f);
        int e = start;
        for (; e + 4 <= end; e += 4) {
            int sA = csr_src[e + sub];
            int sB = csr_src[e + 2 + sub];
            __half2 hA = *reinterpret_cast<const __half2*>(&Wh[(size_t)sA * 64 + sl * 2]);
            __half2 hB = *reinterpret_cast<const __half2*>(&Wh[(size_t)sB * 64 + sl * 2]);
            float2 fA = __half22float2(hA), fB = __half22float2(hB);
            acc.x += fA.x + fB.x; acc.y += fA.y + fB.y;
        }
        if (e + 2 <= end) {
            int s = csr_src[e + sub];
            float2 f = __half22float2(*reinterpret_cast<const __half2*>(&Wh[(size_t)s * 64 + sl * 2]));
            acc.x += f.x; acc.y += f.y;
            e += 2;
        }
        if (e < end && sub == 0) {
            int s = csr_src[e];
            float2 f = __half22float2(*reinterpret_cast<const __half2*>(&Wh[(size_t)s * 64 + sl * 2]));
            acc.x += f.x; acc.y += f.y;
        }
        acc.x += __shfl_xor(acc.x, 32);
        acc.y += __shfl_xor(acc.y, 32);
        if (sub == 0) {
            float2* p = reinterpret_cast<float2*>(&out[(size_t)wid * 64 + sl * 2]);
            if (ACCUM) {
                float2 c = *p;
                c.x += acc.x * inv; c.y += acc.y * inv;
                *p = c;
            } else {
                *p = make_float2(acc.x * inv, acc.y * inv);
            }
        }
    }
}

extern "C" void kernel_launch(void* const* d_in, const int* in_sizes, int n_in,
                              void* d_out, int out_size, void* d_ws, size_t ws_size,
                              hipStream_t stream)
{
    const float* emb_user = (const float*)d_in[0];
    const float* emb_item = (const float*)d_in[1];
    const float* W1_rates    = (const float*)d_in[2];
    const float* b1_rates    = (const float*)d_in[3];
    const float* W1_rated_by = (const float*)d_in[6];
    const float* b1_rated_by = (const float*)d_in[7];
    const float* W2_rated_by = (const float*)d_in[8];
    const float* b2_rated_by = (const float*)d_in[9];
    const float* W1_follows  = (const float*)d_in[10];
    const float* b1_follows  = (const float*)d_in[11];
    const float* W2_follows  = (const float*)d_in[12];
    const float* b2_follows  = (const float*)d_in[13];
    const float* W1_similar  = (const float*)d_in[14];
    const float* b1_similar  = (const float*)d_in[15];
    const int* src_rates    = (const int*)d_in[18];
    const int* dst_rates    = (const int*)d_in[19];
    const int* src_rated_by = (const int*)d_in[20];
    const int* dst_rated_by = (const int*)d_in[21];
    const int* src_follows  = (const int*)d_in[22];
    const int* dst_follows  = (const int*)d_in[23];
    const int* src_similar  = (const int*)d_in[24];
    const int* dst_similar  = (const int*)d_in[25];

    float* out = (float*)d_out;

    // ---- workspace layout ----
    // Wh fp16 25.6MB | acc_i 51.2MB (pairbuf aliases here during CSR build) |
    // acc_u 51.2MB | csr_src 8MB | row_start 1.6MB | bucket_cursor | gstart
    char* base = (char*)d_ws;
    __half* Wh   = (__half*)base;
    float* acc_i = (float*)(base + 25600000);
    float* acc_u = (float*)(base + 25600000 + 51200000);
    int* csr_src   = (int*)(base + 128000000);
    int* row_start = csr_src + 2000000;            // NKEY+1 entries
    int* bucket_cursor = row_start + NKEY + 1;     // NB entries
    int* gstart        = bucket_cursor + 256;      // NB+1 entries
    uint2* pairbuf = (uint2*)acc_i;                // 196*11264*8 = 17.7MB, dead after build

    const int SEG_RATES    = 0;             // rel 0, dst = item
    const int SEG_RATED_BY = 100000;        // rel 1, dst = user
    const int SEG_FOLLOWS  = 200000;        // rel 2, dst = user
    const int SEG_SIMILAR  = 300000;        // rel 3, dst = item

    hipMemsetAsync(bucket_cursor, 0, NB * sizeof(int), stream);

    const int tiles = (NEDGE + TILE - 1) / TILE;   // 123
    partition_kernel<<<dim3(tiles, 4), 256, 0, stream>>>(
        src_rates, dst_rates, src_rated_by, dst_rated_by,
        src_follows, dst_follows, src_similar, dst_similar,
        bucket_cursor, pairbuf);
    bucket_scan<<<1, 256, 0, stream>>>(bucket_cursor, gstart, row_start);
    build_csr<<<NB, 256, 0, stream>>>(pairbuf, bucket_cursor, gstart, row_start, csr_src);

    const int gb = (100000 + 127) / 128;       // MFMA GEMM blocks (BM=128)
    const int pb = (100000 * 64 + 255) / 256;  // pull: 1 wave/row, 4 waves/block

    // ---------------- layer 1 ----------------
    gemm_mfma<128><<<gb, 256, 0, stream>>>(emb_user, W1_rates, b1_rates, Wh, N_USER, 0);
    pull_kernel<128, false><<<pb, 256, 0, stream>>>(Wh, row_start, csr_src, acc_i, SEG_RATES, N_ITEM);
    gemm_mfma<128><<<gb, 256, 0, stream>>>(emb_item, W1_similar, b1_similar, Wh, N_ITEM, 0);
    pull_kernel<128, true><<<pb, 256, 0, stream>>>(Wh, row_start, csr_src, acc_i, SEG_SIMILAR, N_ITEM);
    gemm_mfma<128><<<gb, 256, 0, stream>>>(emb_item, W1_rated_by, b1_rated_by, Wh, N_ITEM, 0);
    pull_kernel<128, false><<<pb, 256, 0, stream>>>(Wh, row_start, csr_src, acc_u, SEG_RATED_BY, N_USER);
    gemm_mfma<128><<<gb, 256, 0, stream>>>(emb_user, W1_follows, b1_follows, Wh, N_USER, 0);
    pull_kernel<128, true><<<pb, 256, 0, stream>>>(Wh, row_start, csr_src, acc_u, SEG_FOLLOWS, N_USER);

    // ---------------- layer 2 (user output only; leaky_relu fused into GEMM A-load) ----------------
    gemm_mfma<64><<<gb, 256, 0, stream>>>(acc_i, W2_rated_by, b2_rated_by, Wh, N_ITEM, 1);
    pull_kernel<64, false><<<pb, 256, 0, stream>>>(Wh, row_start, csr_src, out, SEG_RATED_BY, N_USER);
    gemm_mfma<64><<<gb, 256, 0, stream>>>(acc_u, W2_follows, b2_follows, Wh, N_USER, 1);
    pull_kernel<64, true><<<pb, 256, 0, stream>>>(Wh, row_start, csr_src, out, SEG_FOLLOWS, N_USER);
}

// Round 8
// 382.141 us; speedup vs baseline: 12.0976x; 1.1421x over previous
//
#include <hip/hip_runtime.h>
#include <hip/hip_fp16.h>

#define N_USER 100000
#define N_ITEM 100000
#define NEDGE  500000
#define NKEY   400000          // 4 relations x 100k dst nodes
#define BSHIFT 11              // 2048 keys per bucket
#define NB     196             // ceil(NKEY / 2048)
#define BCAP   11264           // pairs per bucket (mean 10240 -> +10 sigma)
#define TILE   4096

typedef _Float16 f16x8 __attribute__((ext_vector_type(8)));
typedef float    f32x4 __attribute__((ext_vector_type(4)));

// ---------------- weight pre-shuffle: W[128][N] fp32 -> fragment-major fp16 ----------------
// dst chunk=(n>>4)*4+(k>>5), lane=((k>>3)&3)*16+(n&15), e=k&7 ; one f16x8 per (chunk,lane)
__global__ void prep_w(const float* __restrict__ W, __half* __restrict__ dst, int N)
{
    int i = blockIdx.x * 256 + threadIdx.x;
    if (i >= 128 * N) return;
    int k = i / N, n = i % N;
    int chunk = (n >> 4) * 4 + (k >> 5);
    int lane  = ((k >> 3) & 3) * 16 + (n & 15);
    int e     = k & 7;
    dst[(chunk * 64 + lane) * 8 + e] = __float2half(W[i]);
}

// ---------------- fused dual-output MFMA GEMM (layer 1) ----------------
// out0 = A @ W0 + b0 ; out1 = A @ W1 + b1  (A fp32 [M][128], outs fp16 [M][128])
__global__ __launch_bounds__(256, 2)
void gemm2(const float* __restrict__ A,
           const __half* __restrict__ Wf0, const __half* __restrict__ Wf1,
           const float* __restrict__ b0, const float* __restrict__ b1,
           __half* __restrict__ out0, __half* __restrict__ out1, int M)
{
    const int tid = threadIdx.x;
    const int wave = tid >> 6, lane = tid & 63;
    const int l16 = lane & 15, lk = lane >> 4;
    const int rowBase = blockIdx.x * 128 + wave * 32;

    f32x4 acc0[2][8], acc1[2][8];
#pragma unroll
    for (int m = 0; m < 2; ++m)
#pragma unroll
        for (int n = 0; n < 8; ++n) { acc0[m][n] = (f32x4)0.f; acc1[m][n] = (f32x4)0.f; }

#pragma unroll
    for (int kt = 0; kt < 4; ++kt) {
        f16x8 af[2];
#pragma unroll
        for (int m = 0; m < 2; ++m) {
            int gr = rowBase + m * 16 + l16;
            float4 v0 = make_float4(0.f, 0.f, 0.f, 0.f), v1 = v0;
            if (gr < M) {
                const float* p = &A[(size_t)gr * 128 + kt * 32 + lk * 8];
                v0 = *reinterpret_cast<const float4*>(p);
                v1 = *reinterpret_cast<const float4*>(p + 4);
            }
            f16x8 a;
            a[0] = (_Float16)v0.x; a[1] = (_Float16)v0.y;
            a[2] = (_Float16)v0.z; a[3] = (_Float16)v0.w;
            a[4] = (_Float16)v1.x; a[5] = (_Float16)v1.y;
            a[6] = (_Float16)v1.z; a[7] = (_Float16)v1.w;
            af[m] = a;
        }
#pragma unroll
        for (int n = 0; n < 8; ++n) {
            const size_t cidx = (size_t)((n * 4 + kt) * 64 + lane) * 8;
            f16x8 bf0 = *reinterpret_cast<const f16x8*>(Wf0 + cidx);
            f16x8 bf1 = *reinterpret_cast<const f16x8*>(Wf1 + cidx);
            acc0[0][n] = __builtin_amdgcn_mfma_f32_16x16x32_f16(af[0], bf0, acc0[0][n], 0, 0, 0);
            acc0[1][n] = __builtin_amdgcn_mfma_f32_16x16x32_f16(af[1], bf0, acc0[1][n], 0, 0, 0);
            acc1[0][n] = __builtin_amdgcn_mfma_f32_16x16x32_f16(af[0], bf1, acc1[0][n], 0, 0, 0);
            acc1[1][n] = __builtin_amdgcn_mfma_f32_16x16x32_f16(af[1], bf1, acc1[1][n], 0, 0, 0);
        }
    }

#pragma unroll
    for (int m = 0; m < 2; ++m) {
        int gr0 = rowBase + m * 16 + lk * 4;
#pragma unroll
        for (int n = 0; n < 8; ++n) {
            float bv0 = b0[n * 16 + l16];
            float bv1 = b1[n * 16 + l16];
#pragma unroll
            for (int r = 0; r < 4; ++r) {
                int gr = gr0 + r;
                if (gr < M) {
                    out0[(size_t)gr * 128 + n * 16 + l16] = __float2half(acc0[m][n][r] + bv0);
                    out1[(size_t)gr * 128 + n * 16 + l16] = __float2half(acc1[m][n][r] + bv1);
                }
            }
        }
    }
}

// ---------------- layer-2 GEMM: out[M][64] = lrelu(A fp16 [M][128]) @ W + b ----------------
__global__ __launch_bounds__(256, 4)
void gemm1_l2(const __half* __restrict__ A, const __half* __restrict__ Wf,
              const float* __restrict__ bias, __half* __restrict__ out, int M)
{
    const int tid = threadIdx.x;
    const int wave = tid >> 6, lane = tid & 63;
    const int l16 = lane & 15, lk = lane >> 4;
    const int rowBase = blockIdx.x * 128 + wave * 32;

    f32x4 acc[2][4];
#pragma unroll
    for (int m = 0; m < 2; ++m)
#pragma unroll
        for (int n = 0; n < 4; ++n) acc[m][n] = (f32x4)0.f;

#pragma unroll
    for (int kt = 0; kt < 4; ++kt) {
        f16x8 af[2];
#pragma unroll
        for (int m = 0; m < 2; ++m) {
            int gr = rowBase + m * 16 + l16;
            f16x8 a = (f16x8)(_Float16)0.f;
            if (gr < M)
                a = *reinterpret_cast<const f16x8*>(&A[(size_t)gr * 128 + kt * 32 + lk * 8]);
#pragma unroll
            for (int e = 0; e < 8; ++e) {
                float x = (float)a[e];
                x = x > 0.f ? x : 0.01f * x;
                a[e] = (_Float16)x;
            }
            af[m] = a;
        }
#pragma unroll
        for (int n = 0; n < 4; ++n) {
            const size_t cidx = (size_t)((n * 4 + kt) * 64 + lane) * 8;
            f16x8 bf = *reinterpret_cast<const f16x8*>(Wf + cidx);
            acc[0][n] = __builtin_amdgcn_mfma_f32_16x16x32_f16(af[0], bf, acc[0][n], 0, 0, 0);
            acc[1][n] = __builtin_amdgcn_mfma_f32_16x16x32_f16(af[1], bf, acc[1][n], 0, 0, 0);
        }
    }

#pragma unroll
    for (int m = 0; m < 2; ++m) {
        int gr0 = rowBase + m * 16 + lk * 4;
#pragma unroll
        for (int n = 0; n < 4; ++n) {
            float bv = bias[n * 16 + l16];
#pragma unroll
            for (int r = 0; r < 4; ++r) {
                int gr = gr0 + r;
                if (gr < M)
                    out[(size_t)gr * 64 + n * 16 + l16] = __float2half(acc[m][n][r] + bv);
            }
        }
    }
}

// ---------------- pass 1: partition edges into 196 buckets of (key,src) pairs ----------------
__global__ __launch_bounds__(256)
void partition_kernel(const int* __restrict__ s0, const int* __restrict__ d0,
                      const int* __restrict__ s1, const int* __restrict__ d1,
                      const int* __restrict__ s2, const int* __restrict__ d2,
                      const int* __restrict__ s3, const int* __restrict__ d3,
                      int* __restrict__ bucket_cursor, uint2* __restrict__ pairbuf)
{
    __shared__ int cntS[256], lscan[256], gbase[256], cur[256];
    __shared__ uint2 stage[TILE];
    __shared__ unsigned char bslot[TILE];

    const int t = threadIdx.x;
    const int rel = blockIdx.y;
    const int* S = rel == 0 ? s0 : rel == 1 ? s1 : rel == 2 ? s2 : s3;
    const int* D = rel == 0 ? d0 : rel == 1 ? d1 : rel == 2 ? d2 : d3;
    const int tileBase = blockIdx.x * TILE;
    const int tileN = min(TILE, NEDGE - tileBase);

    cntS[t] = 0;
    __syncthreads();

    int key[16], sv[16];
#pragma unroll
    for (int k = 0; k < 16; ++k) {
        int i = tileBase + k * 256 + t;
        if (i < NEDGE) {
            sv[k]  = S[i];
            key[k] = rel * 100000 + D[i];
            atomicAdd(&cntS[key[k] >> BSHIFT], 1);
        } else key[k] = -1;
    }
    __syncthreads();

    const int c = cntS[t];
    lscan[t] = c;
    __syncthreads();
    for (int off = 1; off < 256; off <<= 1) {
        int v = (t >= off) ? lscan[t - off] : 0;
        __syncthreads();
        lscan[t] += v;
        __syncthreads();
    }
    const int ex = lscan[t] - c;
    __syncthreads();
    lscan[t] = ex;
    cur[t]   = ex;
    if (t < NB && c > 0) gbase[t] = atomicAdd(&bucket_cursor[t], c);
    __syncthreads();

#pragma unroll
    for (int k = 0; k < 16; ++k) {
        if (key[k] >= 0) {
            int b = key[k] >> BSHIFT;
            int slot = atomicAdd(&cur[b], 1);
            stage[slot] = make_uint2((unsigned)key[k], (unsigned)sv[k]);
            bslot[slot] = (unsigned char)b;
        }
    }
    __syncthreads();

    for (int j = t; j < tileN; j += 256) {
        int b = bslot[j];
        pairbuf[(size_t)b * BCAP + gbase[b] + (j - lscan[b])] = stage[j];
    }
}

// ---------------- tiny scan of bucket totals ----------------
__global__ __launch_bounds__(256)
void bucket_scan(const int* __restrict__ bucket_cursor, int* __restrict__ gstart,
                 int* __restrict__ row_start)
{
    __shared__ int sd[256];
    int t = threadIdx.x;
    int v = (t < NB) ? bucket_cursor[t] : 0;
    sd[t] = v;
    __syncthreads();
    for (int off = 1; off < 256; off <<= 1) {
        int u = (t >= off) ? sd[t - off] : 0;
        __syncthreads();
        sd[t] += u;
        __syncthreads();
    }
    if (t < NB) gstart[t] = sd[t] - v;        // exclusive
    if (t == NB) gstart[NB] = sd[NB - 1];
    if (t == 0)  row_start[NKEY] = 4 * NEDGE;
}

// ---------------- pass 2: per-bucket bin sort -> row_start + csr_src ----------------
__global__ __launch_bounds__(256)
void build_csr(const uint2* __restrict__ pairbuf, const int* __restrict__ bucket_cursor,
               const int* __restrict__ gstart, int* __restrict__ row_start,
               int* __restrict__ csr_src)
{
    __shared__ int hist[2048];
    __shared__ int scan2[2048];
    __shared__ int partial[256];

    const int b = blockIdx.x;
    const int t = threadIdx.x;
    const int cnt = bucket_cursor[b];
    const int gs  = gstart[b];
    const uint2* pb = pairbuf + (size_t)b * BCAP;
    const int keyBase = b << BSHIFT;
    const int nbin = min(2048, NKEY - keyBase);

    for (int k = t; k < 2048; k += 256) hist[k] = 0;
    __syncthreads();
    for (int j = t; j < cnt; j += 256)
        atomicAdd(&hist[(int)pb[j].x - keyBase], 1);
    __syncthreads();

    const int base8 = t * 8;
    int s = 0;
#pragma unroll
    for (int k = 0; k < 8; ++k) s += hist[base8 + k];
    partial[t] = s;
    __syncthreads();
    for (int off = 1; off < 256; off <<= 1) {
        int u = (t >= off) ? partial[t - off] : 0;
        __syncthreads();
        partial[t] += u;
        __syncthreads();
    }
    int run = partial[t] - s;
#pragma unroll
    for (int k = 0; k < 8; ++k) { scan2[base8 + k] = run; run += hist[base8 + k]; }
    __syncthreads();

    for (int k = t; k < nbin; k += 256) row_start[keyBase + k] = gs + scan2[k];
    for (int k = t; k < 2048; k += 256) hist[k] = scan2[k];
    __syncthreads();

    for (int j = t; j < cnt; j += 256) {
        uint2 p = pb[j];
        int pos = atomicAdd(&hist[(int)p.x - keyBase], 1);
        csr_src[gs + pos] = (int)p.y;
    }
}

// ---------------- pull: one wave per dst row, 2 edges per half-wave pair ----------------
// out[row] (ACCUM? += : =) mean_{e in row} Wh[csr_src[e]] ; out fp16 if HOUT else fp32
template<int D, bool ACCUM, bool HOUT>
__global__ __launch_bounds__(256)
void pull_kernel(const __half* __restrict__ Wh, const int* __restrict__ row_start,
                 const int* __restrict__ csr_src, void* __restrict__ outv,
                 int segBase, int nRows)
{
    int wid = (blockIdx.x * blockDim.x + threadIdx.x) >> 6;
    int lane = threadIdx.x & 63;
    if (wid >= nRows) return;
    int idx = segBase + wid;
    int start = row_start[idx];
    int end   = row_start[idx + 1];
    float inv = 1.0f / (float)max(end - start, 1);
    int sub = lane >> 5;
    int sl  = lane & 31;

    if (D == 128) {
        float4 acc = make_float4(0.f, 0.f, 0.f, 0.f);
        int e = start;
        for (; e + 4 <= end; e += 4) {
            int sA = csr_src[e + sub];
            int sB = csr_src[e + 2 + sub];
            uint2 uA = *reinterpret_cast<const uint2*>(&Wh[(size_t)sA * 128 + sl * 4]);
            uint2 uB = *reinterpret_cast<const uint2*>(&Wh[(size_t)sB * 128 + sl * 4]);
            float2 fa0 = __half22float2(*reinterpret_cast<__half2*>(&uA.x));
            float2 fa1 = __half22float2(*reinterpret_cast<__half2*>(&uA.y));
            float2 fb0 = __half22float2(*reinterpret_cast<__half2*>(&uB.x));
            float2 fb1 = __half22float2(*reinterpret_cast<__half2*>(&uB.y));
            acc.x += fa0.x + fb0.x; acc.y += fa0.y + fb0.y;
            acc.z += fa1.x + fb1.x; acc.w += fa1.y + fb1.y;
        }
        if (e + 2 <= end) {
            int s = csr_src[e + sub];
            uint2 u = *reinterpret_cast<const uint2*>(&Wh[(size_t)s * 128 + sl * 4]);
            float2 f0 = __half22float2(*reinterpret_cast<__half2*>(&u.x));
            float2 f1 = __half22float2(*reinterpret_cast<__half2*>(&u.y));
            acc.x += f0.x; acc.y += f0.y; acc.z += f1.x; acc.w += f1.y;
            e += 2;
        }
        if (e < end && sub == 0) {
            int s = csr_src[e];
            uint2 u = *reinterpret_cast<const uint2*>(&Wh[(size_t)s * 128 + sl * 4]);
            float2 f0 = __half22float2(*reinterpret_cast<__half2*>(&u.x));
            float2 f1 = __half22float2(*reinterpret_cast<__half2*>(&u.y));
            acc.x += f0.x; acc.y += f0.y; acc.z += f1.x; acc.w += f1.y;
        }
        acc.x += __shfl_xor(acc.x, 32);
        acc.y += __shfl_xor(acc.y, 32);
        acc.z += __shfl_xor(acc.z, 32);
        acc.w += __shfl_xor(acc.w, 32);
        if (sub == 0) {
            acc.x *= inv; acc.y *= inv; acc.z *= inv; acc.w *= inv;
            if constexpr (HOUT) {
                __half* o = (__half*)outv + (size_t)wid * 128 + sl * 4;
                if (ACCUM) {
                    uint2 cur = *reinterpret_cast<const uint2*>(o);
                    float2 c0 = __half22float2(*reinterpret_cast<__half2*>(&cur.x));
                    float2 c1 = __half22float2(*reinterpret_cast<__half2*>(&cur.y));
                    acc.x += c0.x; acc.y += c0.y; acc.z += c1.x; acc.w += c1.y;
                }
                uint2 st;
                *reinterpret_cast<__half2*>(&st.x) = __floats2half2_rn(acc.x, acc.y);
                *reinterpret_cast<__half2*>(&st.y) = __floats2half2_rn(acc.z, acc.w);
                *reinterpret_cast<uint2*>(o) = st;
            } else {
                float* o = (float*)outv + (size_t)wid * 128 + sl * 4;
                float4* p = reinterpret_cast<float4*>(o);
                if (ACCUM) {
                    float4 c = *p;
                    c.x += acc.x; c.y += acc.y; c.z += acc.z; c.w += acc.w;
                    *p = c;
                } else {
                    *p = acc;
                }
            }
        }
    } else {
        float2 acc = make_float2(0.f, 0.f);
        int e = start;
        for (; e + 4 <= end; e += 4) {
            int sA = csr_src[e + sub];
            int sB = csr_src[e + 2 + sub];
            float2 fA = __half22float2(*reinterpret_cast<const __half2*>(&Wh[(size_t)sA * 64 + sl * 2]));
            float2 fB = __half22float2(*reinterpret_cast<const __half2*>(&Wh[(size_t)sB * 64 + sl * 2]));
            acc.x += fA.x + fB.x; acc.y += fA.y + fB.y;
        }
        if (e + 2 <= end) {
            int s = csr_src[e + sub];
            float2 f = __half22float2(*reinterpret_cast<const __half2*>(&Wh[(size_t)s * 64 + sl * 2]));
            acc.x += f.x; acc.y += f.y;
            e += 2;
        }
        if (e < end && sub == 0) {
            int s = csr_src[e];
            float2 f = __half22float2(*reinterpret_cast<const __half2*>(&Wh[(size_t)s * 64 + sl * 2]));
            acc.x += f.x; acc.y += f.y;
        }
        acc.x += __shfl_xor(acc.x, 32);
        acc.y += __shfl_xor(acc.y, 32);
        if (sub == 0) {
            acc.x *= inv; acc.y *= inv;
            if constexpr (HOUT) {
                __half* o = (__half*)outv + (size_t)wid * 64 + sl * 2;
                if (ACCUM) {
                    __half2 cur = *reinterpret_cast<const __half2*>(o);
                    float2 c = __half22float2(cur);
                    acc.x += c.x; acc.y += c.y;
                }
                *reinterpret_cast<__half2*>(o) = __floats2half2_rn(acc.x, acc.y);
            } else {
                float2* p = reinterpret_cast<float2*>((float*)outv + (size_t)wid * 64 + sl * 2);
                if (ACCUM) {
                    float2 c = *p;
                    c.x += acc.x; c.y += acc.y;
                    *p = c;
                } else {
                    *p = make_float2(acc.x, acc.y);
                }
            }
        }
    }
}

extern "C" void kernel_launch(void* const* d_in, const int* in_sizes, int n_in,
                              void* d_out, int out_size, void* d_ws, size_t ws_size,
                              hipStream_t stream)
{
    const float* emb_user = (const float*)d_in[0];
    const float* emb_item = (const float*)d_in[1];
    const float* W1_rates    = (const float*)d_in[2];
    const float* b1_rates    = (const float*)d_in[3];
    const float* W1_rated_by = (const float*)d_in[6];
    const float* b1_rated_by = (const float*)d_in[7];
    const float* W2_rated_by = (const float*)d_in[8];
    const float* b2_rated_by = (const float*)d_in[9];
    const float* W1_follows  = (const float*)d_in[10];
    const float* b1_follows  = (const float*)d_in[11];
    const float* W2_follows  = (const float*)d_in[12];
    const float* b2_follows  = (const float*)d_in[13];
    const float* W1_similar  = (const float*)d_in[14];
    const float* b1_similar  = (const float*)d_in[15];
    const int* src_rates    = (const int*)d_in[18];
    const int* dst_rates    = (const int*)d_in[19];
    const int* src_rated_by = (const int*)d_in[20];
    const int* dst_rated_by = (const int*)d_in[21];
    const int* src_follows  = (const int*)d_in[22];
    const int* dst_follows  = (const int*)d_in[23];
    const int* src_similar  = (const int*)d_in[24];
    const int* dst_similar  = (const int*)d_in[25];

    float* out = (float*)d_out;

    // ---- workspace layout (bytes) — FIXED: fp16 [100k][128] = 25.6 MB each ----
    // WhX  fp16 [100k][128] : 0           .. 25,600,000   (pairbuf 17.7MB aliases here during CSR build)
    // WhY  fp16 [100k][128] : 25,600,000  .. 51,200,000
    // accI fp16 [100k][128] : 51,200,000  .. 76,800,000
    // accU fp16 [100k][128] : 76,800,000  .. 102,400,000
    // csr_src  int[2M]      : 102,400,000 .. 110,400,000
    // row_start int[400001] : 110,400,000 .. 112,000,004
    // bucket_cursor         : 112,000,016 (256 ints)
    // gstart                : 112,001,056 (NB+1 ints)
    // wfrag (6 matrices)    : 112,002,080 .. 112,165,920
    char* base = (char*)d_ws;
    __half* WhX  = (__half*)base;
    __half* WhY  = (__half*)(base + 25600000);
    __half* accI = (__half*)(base + 51200000);
    __half* accU = (__half*)(base + 76800000);
    int* csr_src   = (int*)(base + 102400000);
    int* row_start = (int*)(base + 110400000);          // NKEY+1 ints
    int* bucket_cursor = (int*)(base + 112000016);      // 256 ints
    int* gstart        = (int*)(base + 112001056);      // NB+1 ints
    __half* wf = (__half*)(base + 112002080);
    __half* wf_rates    = wf;
    __half* wf_follows  = wf + 16384;
    __half* wf_similar  = wf + 32768;
    __half* wf_rated_by = wf + 49152;
    __half* wf2_rb      = wf + 65536;   // 128x64
    __half* wf2_f       = wf + 73728;
    uint2* pairbuf = (uint2*)WhX;       // dead before first gemm2 writes WhX

    const int SEG_RATES    = 0;             // rel 0, dst = item
    const int SEG_RATED_BY = 100000;        // rel 1, dst = user
    const int SEG_FOLLOWS  = 200000;        // rel 2, dst = user
    const int SEG_SIMILAR  = 300000;        // rel 3, dst = item

    hipMemsetAsync(bucket_cursor, 0, 256 * sizeof(int), stream);

    // weight pre-shuffle (tiny, independent)
    prep_w<<<64, 256, 0, stream>>>(W1_rates,    wf_rates,    128);
    prep_w<<<64, 256, 0, stream>>>(W1_follows,  wf_follows,  128);
    prep_w<<<64, 256, 0, stream>>>(W1_similar,  wf_similar,  128);
    prep_w<<<64, 256, 0, stream>>>(W1_rated_by, wf_rated_by, 128);
    prep_w<<<32, 256, 0, stream>>>(W2_rated_by, wf2_rb, 64);
    prep_w<<<32, 256, 0, stream>>>(W2_follows,  wf2_f,  64);

    // CSR build
    const int tiles = (NEDGE + TILE - 1) / TILE;   // 123
    partition_kernel<<<dim3(tiles, 4), 256, 0, stream>>>(
        src_rates, dst_rates, src_rated_by, dst_rated_by,
        src_follows, dst_follows, src_similar, dst_similar,
        bucket_cursor, pairbuf);
    bucket_scan<<<1, 256, 0, stream>>>(bucket_cursor, gstart, row_start);
    build_csr<<<NB, 256, 0, stream>>>(pairbuf, bucket_cursor, gstart, row_start, csr_src);

    const int gb = (100000 + 127) / 128;       // 782
    const int pb = (100000 * 64 + 255) / 256;  // pull: 1 wave/row

    // ---------------- layer 1 ----------------
    gemm2<<<gb, 256, 0, stream>>>(emb_user, wf_rates, wf_follows, b1_rates, b1_follows,
                                  WhX, WhY, N_USER);
    pull_kernel<128, false, true><<<pb, 256, 0, stream>>>(WhX, row_start, csr_src, accI, SEG_RATES, N_ITEM);
    pull_kernel<128, false, true><<<pb, 256, 0, stream>>>(WhY, row_start, csr_src, accU, SEG_FOLLOWS, N_USER);
    gemm2<<<gb, 256, 0, stream>>>(emb_item, wf_similar, wf_rated_by, b1_similar, b1_rated_by,
                                  WhX, WhY, N_ITEM);
    pull_kernel<128, true, true><<<pb, 256, 0, stream>>>(WhX, row_start, csr_src, accI, SEG_SIMILAR, N_ITEM);
    pull_kernel<128, true, true><<<pb, 256, 0, stream>>>(WhY, row_start, csr_src, accU, SEG_RATED_BY, N_USER);

    // ---------------- layer 2 (user output only; lrelu fused into GEMM A-load) ----------------
    gemm1_l2<<<gb, 256, 0, stream>>>(accI, wf2_rb, b2_rated_by, WhX, N_ITEM);
    pull_kernel<64, false, false><<<pb, 256, 0, stream>>>(WhX, row_start, csr_src, out, SEG_RATED_BY, N_USER);
    gemm1_l2<<<gb, 256, 0, stream>>>(accU, wf2_f, b2_follows, WhY, N_USER);
    pull_kernel<64, true, false><<<pb, 256, 0, stream>>>(WhY, row_start, csr_src, out, SEG_FOLLOWS, N_USER);
}

// Round 9
// 331.602 us; speedup vs baseline: 13.9414x; 1.1524x over previous
//
#include <hip/hip_runtime.h>
#include <hip/hip_fp16.h>

#define N_USER 100000
#define N_ITEM 100000
#define NEDGE  500000
#define NKEY   400000          // 4 relations x 100k dst nodes
#define BSHIFT 11              // 2048 keys per bucket
#define NB     196             // ceil(NKEY / 2048)
#define BCAP   11264           // pairs per bucket (mean 10240 -> +10 sigma)
#define TILE   4096

#define SEG_RATES    0
#define SEG_RATED_BY 100000
#define SEG_FOLLOWS  200000
#define SEG_SIMILAR  300000

typedef _Float16 f16x8 __attribute__((ext_vector_type(8)));
typedef float    f32x4 __attribute__((ext_vector_type(4)));

// ---------------- weight pre-shuffle (all 6 matrices, one dispatch) ----------------
// dst chunk=(n>>4)*4+(k>>5), lane=((k>>3)&3)*16+(n&15), e=k&7
__global__ void prep_w_all(const float* __restrict__ W0, const float* __restrict__ W1,
                           const float* __restrict__ W2, const float* __restrict__ W3,
                           const float* __restrict__ W4, const float* __restrict__ W5,
                           __half* __restrict__ D0, __half* __restrict__ D1,
                           __half* __restrict__ D2, __half* __restrict__ D3,
                           __half* __restrict__ D4, __half* __restrict__ D5)
{
    int y = blockIdx.y;
    const float* W = y == 0 ? W0 : y == 1 ? W1 : y == 2 ? W2 : y == 3 ? W3 : y == 4 ? W4 : W5;
    __half* dst    = y == 0 ? D0 : y == 1 ? D1 : y == 2 ? D2 : y == 3 ? D3 : y == 4 ? D4 : D5;
    int N = y < 4 ? 128 : 64;
    int i = blockIdx.x * 256 + threadIdx.x;
    if (i >= 128 * N) return;
    int k = i / N, n = i % N;
    int chunk = (n >> 4) * 4 + (k >> 5);
    int lane  = ((k >> 3) & 3) * 16 + (n & 15);
    int e     = k & 7;
    dst[(chunk * 64 + lane) * 8 + e] = __float2half(W[i]);
}

// ---------------- dual-output MFMA GEMM, 64-row blocks, A fully preloaded ----------------
__global__ __launch_bounds__(256, 3)
void gemm2(const float* __restrict__ A,
           const __half* __restrict__ Wf0, const __half* __restrict__ Wf1,
           const float* __restrict__ b0, const float* __restrict__ b1,
           __half* __restrict__ out0, __half* __restrict__ out1, int M)
{
    const int tid = threadIdx.x;
    const int wave = tid >> 6, lane = tid & 63;
    const int l16 = lane & 15, lk = lane >> 4;
    const int rowBase = blockIdx.x * 64 + wave * 16;

    f32x4 acc0[8], acc1[8];
#pragma unroll
    for (int n = 0; n < 8; ++n) { acc0[n] = (f32x4)0.f; acc1[n] = (f32x4)0.f; }

    // preload the wave's entire A slice (16 rows x 128 cols): 8 float4 per lane
    const int gr = rowBase + l16;
    const bool valid = gr < M;
    const float* ap = A + (size_t)(valid ? gr : 0) * 128 + lk * 8;
    float4 av[8];
#pragma unroll
    for (int kt = 0; kt < 4; ++kt) {
        av[2 * kt]     = *reinterpret_cast<const float4*>(ap + kt * 32);
        av[2 * kt + 1] = *reinterpret_cast<const float4*>(ap + kt * 32 + 4);
    }
    if (!valid) {
#pragma unroll
        for (int j = 0; j < 8; ++j) av[j] = make_float4(0.f, 0.f, 0.f, 0.f);
    }

#pragma unroll
    for (int kt = 0; kt < 4; ++kt) {
        f16x8 af;
        af[0] = (_Float16)av[2 * kt].x;     af[1] = (_Float16)av[2 * kt].y;
        af[2] = (_Float16)av[2 * kt].z;     af[3] = (_Float16)av[2 * kt].w;
        af[4] = (_Float16)av[2 * kt + 1].x; af[5] = (_Float16)av[2 * kt + 1].y;
        af[6] = (_Float16)av[2 * kt + 1].z; af[7] = (_Float16)av[2 * kt + 1].w;
#pragma unroll
        for (int n = 0; n < 8; ++n) {
            const size_t cidx = (size_t)((n * 4 + kt) * 64 + lane) * 8;
            f16x8 bf0 = *reinterpret_cast<const f16x8*>(Wf0 + cidx);
            f16x8 bf1 = *reinterpret_cast<const f16x8*>(Wf1 + cidx);
            acc0[n] = __builtin_amdgcn_mfma_f32_16x16x32_f16(af, bf0, acc0[n], 0, 0, 0);
            acc1[n] = __builtin_amdgcn_mfma_f32_16x16x32_f16(af, bf1, acc1[n], 0, 0, 0);
        }
    }

    // epilogue: D[row=lk*4+r][col=n*16+l16]
    const int gr0 = rowBase + lk * 4;
#pragma unroll
    for (int n = 0; n < 8; ++n) {
        float bv0 = b0[n * 16 + l16];
        float bv1 = b1[n * 16 + l16];
#pragma unroll
        for (int r = 0; r < 4; ++r) {
            int grr = gr0 + r;
            if (grr < M) {
                out0[(size_t)grr * 128 + n * 16 + l16] = __float2half(acc0[n][r] + bv0);
                out1[(size_t)grr * 128 + n * 16 + l16] = __float2half(acc1[n][r] + bv1);
            }
        }
    }
}

// ---------------- fused pair of layer-2 GEMMs: out[M][64] = lrelu(A fp16) @ W + b ----------------
__global__ __launch_bounds__(256, 4)
void gemm1_l2_pair(const __half* __restrict__ A0, const __half* __restrict__ A1,
                   const __half* __restrict__ Wf0, const __half* __restrict__ Wf1,
                   const float* __restrict__ bias0, const float* __restrict__ bias1,
                   __half* __restrict__ O0, __half* __restrict__ O1, int M)
{
    const __half* A  = blockIdx.y ? A1 : A0;
    const __half* Wf = blockIdx.y ? Wf1 : Wf0;
    const float* bias = blockIdx.y ? bias1 : bias0;
    __half* out = blockIdx.y ? O1 : O0;

    const int tid = threadIdx.x;
    const int wave = tid >> 6, lane = tid & 63;
    const int l16 = lane & 15, lk = lane >> 4;
    const int rowBase = blockIdx.x * 128 + wave * 32;

    f32x4 acc[2][4];
#pragma unroll
    for (int m = 0; m < 2; ++m)
#pragma unroll
        for (int n = 0; n < 4; ++n) acc[m][n] = (f32x4)0.f;

#pragma unroll
    for (int kt = 0; kt < 4; ++kt) {
        f16x8 af[2];
#pragma unroll
        for (int m = 0; m < 2; ++m) {
            int gr = rowBase + m * 16 + l16;
            f16x8 a = (f16x8)(_Float16)0.f;
            if (gr < M)
                a = *reinterpret_cast<const f16x8*>(&A[(size_t)gr * 128 + kt * 32 + lk * 8]);
#pragma unroll
            for (int e = 0; e < 8; ++e) {
                float x = (float)a[e];
                x = x > 0.f ? x : 0.01f * x;
                a[e] = (_Float16)x;
            }
            af[m] = a;
        }
#pragma unroll
        for (int n = 0; n < 4; ++n) {
            const size_t cidx = (size_t)((n * 4 + kt) * 64 + lane) * 8;
            f16x8 bf = *reinterpret_cast<const f16x8*>(Wf + cidx);
            acc[0][n] = __builtin_amdgcn_mfma_f32_16x16x32_f16(af[0], bf, acc[0][n], 0, 0, 0);
            acc[1][n] = __builtin_amdgcn_mfma_f32_16x16x32_f16(af[1], bf, acc[1][n], 0, 0, 0);
        }
    }

#pragma unroll
    for (int m = 0; m < 2; ++m) {
        int gr0 = rowBase + m * 16 + lk * 4;
#pragma unroll
        for (int n = 0; n < 4; ++n) {
            float bv = bias[n * 16 + l16];
#pragma unroll
            for (int r = 0; r < 4; ++r) {
                int gr = gr0 + r;
                if (gr < M)
                    out[(size_t)gr * 64 + n * 16 + l16] = __float2half(acc[m][n][r] + bv);
            }
        }
    }
}

// ---------------- pass 1: partition edges into 196 buckets of (key,src) pairs ----------------
__global__ __launch_bounds__(256)
void partition_kernel(const int* __restrict__ s0, const int* __restrict__ d0,
                      const int* __restrict__ s1, const int* __restrict__ d1,
                      const int* __restrict__ s2, const int* __restrict__ d2,
                      const int* __restrict__ s3, const int* __restrict__ d3,
                      int* __restrict__ bucket_cursor, uint2* __restrict__ pairbuf)
{
    __shared__ int cntS[256], lscan[256], gbase[256], cur[256];
    __shared__ uint2 stage[TILE];
    __shared__ unsigned char bslot[TILE];

    const int t = threadIdx.x;
    const int rel = blockIdx.y;
    const int* S = rel == 0 ? s0 : rel == 1 ? s1 : rel == 2 ? s2 : s3;
    const int* D = rel == 0 ? d0 : rel == 1 ? d1 : rel == 2 ? d2 : d3;
    const int tileBase = blockIdx.x * TILE;
    const int tileN = min(TILE, NEDGE - tileBase);

    cntS[t] = 0;
    __syncthreads();

    int key[16], sv[16];
#pragma unroll
    for (int k = 0; k < 16; ++k) {
        int i = tileBase + k * 256 + t;
        if (i < NEDGE) {
            sv[k]  = S[i];
            key[k] = rel * 100000 + D[i];
            atomicAdd(&cntS[key[k] >> BSHIFT], 1);
        } else key[k] = -1;
    }
    __syncthreads();

    const int c = cntS[t];
    lscan[t] = c;
    __syncthreads();
    for (int off = 1; off < 256; off <<= 1) {
        int v = (t >= off) ? lscan[t - off] : 0;
        __syncthreads();
        lscan[t] += v;
        __syncthreads();
    }
    const int ex = lscan[t] - c;
    __syncthreads();
    lscan[t] = ex;
    cur[t]   = ex;
    if (t < NB && c > 0) gbase[t] = atomicAdd(&bucket_cursor[t], c);
    __syncthreads();

#pragma unroll
    for (int k = 0; k < 16; ++k) {
        if (key[k] >= 0) {
            int b = key[k] >> BSHIFT;
            int slot = atomicAdd(&cur[b], 1);
            stage[slot] = make_uint2((unsigned)key[k], (unsigned)sv[k]);
            bslot[slot] = (unsigned char)b;
        }
    }
    __syncthreads();

    for (int j = t; j < tileN; j += 256) {
        int b = bslot[j];
        pairbuf[(size_t)b * BCAP + gbase[b] + (j - lscan[b])] = stage[j];
    }
}

// ---------------- tiny scan of bucket totals ----------------
__global__ __launch_bounds__(256)
void bucket_scan(const int* __restrict__ bucket_cursor, int* __restrict__ gstart,
                 int* __restrict__ row_start)
{
    __shared__ int sd[256];
    int t = threadIdx.x;
    int v = (t < NB) ? bucket_cursor[t] : 0;
    sd[t] = v;
    __syncthreads();
    for (int off = 1; off < 256; off <<= 1) {
        int u = (t >= off) ? sd[t - off] : 0;
        __syncthreads();
        sd[t] += u;
        __syncthreads();
    }
    if (t < NB) gstart[t] = sd[t] - v;        // exclusive
    if (t == NB) gstart[NB] = sd[NB - 1];
    if (t == 0)  row_start[NKEY] = 4 * NEDGE;
}

// ---------------- pass 2: per-bucket bin sort -> row_start + csr_src ----------------
__global__ __launch_bounds__(256)
void build_csr(const uint2* __restrict__ pairbuf, const int* __restrict__ bucket_cursor,
               const int* __restrict__ gstart, int* __restrict__ row_start,
               int* __restrict__ csr_src)
{
    __shared__ int hist[2048];
    __shared__ int scan2[2048];
    __shared__ int partial[256];

    const int b = blockIdx.x;
    const int t = threadIdx.x;
    const int cnt = bucket_cursor[b];
    const int gs  = gstart[b];
    const uint2* pb = pairbuf + (size_t)b * BCAP;
    const int keyBase = b << BSHIFT;
    const int nbin = min(2048, NKEY - keyBase);

    for (int k = t; k < 2048; k += 256) hist[k] = 0;
    __syncthreads();
    for (int j = t; j < cnt; j += 256)
        atomicAdd(&hist[(int)pb[j].x - keyBase], 1);
    __syncthreads();

    const int base8 = t * 8;
    int s = 0;
#pragma unroll
    for (int k = 0; k < 8; ++k) s += hist[base8 + k];
    partial[t] = s;
    __syncthreads();
    for (int off = 1; off < 256; off <<= 1) {
        int u = (t >= off) ? partial[t - off] : 0;
        __syncthreads();
        partial[t] += u;
        __syncthreads();
    }
    int run = partial[t] - s;
#pragma unroll
    for (int k = 0; k < 8; ++k) { scan2[base8 + k] = run; run += hist[base8 + k]; }
    __syncthreads();

    for (int k = t; k < nbin; k += 256) row_start[keyBase + k] = gs + scan2[k];
    for (int k = t; k < 2048; k += 256) hist[k] = scan2[k];
    __syncthreads();

    for (int j = t; j < cnt; j += 256) {
        uint2 p = pb[j];
        int pos = atomicAdd(&hist[(int)p.x - keyBase], 1);
        csr_src[gs + pos] = (int)p.y;
    }
}

// ---------------- fused pair of 128-wide pulls; 16-lane groups (4 edges in flight) ------
// y=0: out=mean_seg(Wh) for (WhA,segA,outA) ; y=1: (WhB,segB,outB). fp16 out.
template<bool ACCUM>
__global__ __launch_bounds__(256)
void pull128_pair(const __half* __restrict__ WhA, int segA, __half* __restrict__ outA,
                  const __half* __restrict__ WhB, int segB, __half* __restrict__ outB,
                  const int* __restrict__ row_start, const int* __restrict__ csr_src)
{
    const __half* Wh = blockIdx.y ? WhB : WhA;
    __half* out      = blockIdx.y ? outB : outA;
    const int seg    = blockIdx.y ? segB : segA;

    const int wid = (blockIdx.x * 256 + threadIdx.x) >> 6;
    if (wid >= 100000) return;
    const int g  = (threadIdx.x >> 4) & 3;
    const int sl = threadIdx.x & 15;
    const int idx = seg + wid;
    const int s0 = row_start[idx], s1 = row_start[idx + 1];
    const float inv = 1.0f / (float)max(s1 - s0, 1);

    float acc[8];
#pragma unroll
    for (int j = 0; j < 8; ++j) acc[j] = 0.f;

    for (int e = s0 + g; e < s1; e += 4) {
        int src = csr_src[e];
        uint4 u = *reinterpret_cast<const uint4*>(&Wh[(size_t)src * 128 + sl * 8]);
        const __half2* hp = reinterpret_cast<const __half2*>(&u);
#pragma unroll
        for (int j = 0; j < 4; ++j) {
            float2 f = __half22float2(hp[j]);
            acc[2 * j] += f.x; acc[2 * j + 1] += f.y;
        }
    }
#pragma unroll
    for (int j = 0; j < 8; ++j) {
        acc[j] += __shfl_xor(acc[j], 16);
        acc[j] += __shfl_xor(acc[j], 32);
        acc[j] *= inv;
    }
    if (g == 0) {
        __half* o = out + (size_t)wid * 128 + sl * 8;
        if (ACCUM) {
            uint4 c = *reinterpret_cast<const uint4*>(o);
            const __half2* cp = reinterpret_cast<const __half2*>(&c);
#pragma unroll
            for (int j = 0; j < 4; ++j) {
                float2 f = __half22float2(cp[j]);
                acc[2 * j] += f.x; acc[2 * j + 1] += f.y;
            }
        }
        uint4 st;
        __half2* sp = reinterpret_cast<__half2*>(&st);
#pragma unroll
        for (int j = 0; j < 4; ++j) sp[j] = __floats2half2_rn(acc[2 * j], acc[2 * j + 1]);
        *reinterpret_cast<uint4*>(o) = st;
    }
}

// ---------------- final dual-segment pull: out = mean_rb(WhRB) + mean_f(WhF), fp32 ------
// groups 0,1 -> rated_by ; groups 2,3 -> follows ; 16 lanes x 8B cover one 64-wide row
__global__ __launch_bounds__(256)
void dual_pull64(const __half* __restrict__ WhRB, const __half* __restrict__ WhF,
                 const int* __restrict__ row_start, const int* __restrict__ csr_src,
                 float* __restrict__ out)
{
    const int wid = (blockIdx.x * 256 + threadIdx.x) >> 6;
    if (wid >= N_USER) return;
    const int g  = (threadIdx.x >> 4) & 3;
    const int sl = threadIdx.x & 15;

    const int rb0 = row_start[SEG_RATED_BY + wid], rb1 = row_start[SEG_RATED_BY + wid + 1];
    const int f0  = row_start[SEG_FOLLOWS  + wid], f1  = row_start[SEG_FOLLOWS  + wid + 1];
    const float invRB = 1.0f / (float)max(rb1 - rb0, 1);
    const float invF  = 1.0f / (float)max(f1 - f0, 1);

    const __half* Wh = (g < 2) ? WhRB : WhF;
    const int e0 = (g < 2) ? rb0 + (g & 1) : f0 + (g & 1);
    const int e1 = (g < 2) ? rb1 : f1;

    float acc[4] = {0.f, 0.f, 0.f, 0.f};
    for (int e = e0; e < e1; e += 2) {
        int src = csr_src[e];
        uint2 u = *reinterpret_cast<const uint2*>(&Wh[(size_t)src * 64 + sl * 4]);
        const __half2* hp = reinterpret_cast<const __half2*>(&u);
        float2 fa = __half22float2(hp[0]);
        float2 fb = __half22float2(hp[1]);
        acc[0] += fa.x; acc[1] += fa.y; acc[2] += fb.x; acc[3] += fb.y;
    }
    const float sc = (g < 2) ? invRB : invF;
#pragma unroll
    for (int j = 0; j < 4; ++j) {
        acc[j] += __shfl_xor(acc[j], 16);   // combine the 2 groups of the same segment
        acc[j] *= sc;                       // per-segment mean
        acc[j] += __shfl_xor(acc[j], 32);   // rb + f
    }
    if (g == 0) {
        float4 v = make_float4(acc[0], acc[1], acc[2], acc[3]);
        *reinterpret_cast<float4*>(&out[(size_t)wid * 64 + sl * 4]) = v;
    }
}

extern "C" void kernel_launch(void* const* d_in, const int* in_sizes, int n_in,
                              void* d_out, int out_size, void* d_ws, size_t ws_size,
                              hipStream_t stream)
{
    const float* emb_user = (const float*)d_in[0];
    const float* emb_item = (const float*)d_in[1];
    const float* W1_rates    = (const float*)d_in[2];
    const float* b1_rates    = (const float*)d_in[3];
    const float* W1_rated_by = (const float*)d_in[6];
    const float* b1_rated_by = (const float*)d_in[7];
    const float* W2_rated_by = (const float*)d_in[8];
    const float* b2_rated_by = (const float*)d_in[9];
    const float* W1_follows  = (const float*)d_in[10];
    const float* b1_follows  = (const float*)d_in[11];
    const float* W2_follows  = (const float*)d_in[12];
    const float* b2_follows  = (const float*)d_in[13];
    const float* W1_similar  = (const float*)d_in[14];
    const float* b1_similar  = (const float*)d_in[15];
    const int* src_rates    = (const int*)d_in[18];
    const int* dst_rates    = (const int*)d_in[19];
    const int* src_rated_by = (const int*)d_in[20];
    const int* dst_rated_by = (const int*)d_in[21];
    const int* src_follows  = (const int*)d_in[22];
    const int* dst_follows  = (const int*)d_in[23];
    const int* src_similar  = (const int*)d_in[24];
    const int* dst_similar  = (const int*)d_in[25];

    float* out = (float*)d_out;

    // ---- workspace layout (bytes) ----
    // WhX  fp16 [100k][128] : 0           (pairbuf 17.7MB aliases here during CSR build)
    // WhY  fp16 [100k][128] : 25,600,000
    // accI fp16 [100k][128] : 51,200,000
    // accU fp16 [100k][128] : 76,800,000
    // csr_src  int[2M]      : 102,400,000
    // row_start int[400001] : 110,400,000
    // bucket_cursor         : 112,000,016 (256 ints)
    // gstart                : 112,001,056 (NB+1 ints)
    // wfrag (6 matrices)    : 112,002,080
    char* base = (char*)d_ws;
    __half* WhX  = (__half*)base;
    __half* WhY  = (__half*)(base + 25600000);
    __half* accI = (__half*)(base + 51200000);
    __half* accU = (__half*)(base + 76800000);
    int* csr_src   = (int*)(base + 102400000);
    int* row_start = (int*)(base + 110400000);
    int* bucket_cursor = (int*)(base + 112000016);
    int* gstart        = (int*)(base + 112001056);
    __half* wf = (__half*)(base + 112002080);
    __half* wf_rates    = wf;
    __half* wf_follows  = wf + 16384;
    __half* wf_similar  = wf + 32768;
    __half* wf_rated_by = wf + 49152;
    __half* wf2_rb      = wf + 65536;   // 128x64
    __half* wf2_f       = wf + 73728;
    uint2* pairbuf = (uint2*)WhX;       // dead before first gemm2 writes WhX

    hipMemsetAsync(bucket_cursor, 0, 256 * sizeof(int), stream);

    prep_w_all<<<dim3(64, 6), 256, 0, stream>>>(
        W1_rates, W1_follows, W1_similar, W1_rated_by, W2_rated_by, W2_follows,
        wf_rates, wf_follows, wf_similar, wf_rated_by, wf2_rb, wf2_f);

    const int tiles = (NEDGE + TILE - 1) / TILE;   // 123
    partition_kernel<<<dim3(tiles, 4), 256, 0, stream>>>(
        src_rates, dst_rates, src_rated_by, dst_rated_by,
        src_follows, dst_follows, src_similar, dst_similar,
        bucket_cursor, pairbuf);
    bucket_scan<<<1, 256, 0, stream>>>(bucket_cursor, gstart, row_start);
    build_csr<<<NB, 256, 0, stream>>>(pairbuf, bucket_cursor, gstart, row_start, csr_src);

    const int gb2 = (100000 + 63) / 64;        // 1563 (gemm2, 64-row blocks)
    const int gbl = (100000 + 127) / 128;      // 782  (gemm1_l2_pair)
    const int pb  = (100000 + 3) / 4;          // 25000 (pulls: 4 waves/block, 1 row/wave)

    // ---------------- layer 1 ----------------
    gemm2<<<gb2, 256, 0, stream>>>(emb_user, wf_rates, wf_follows, b1_rates, b1_follows,
                                   WhX, WhY, N_USER);
    pull128_pair<false><<<dim3(pb, 2), 256, 0, stream>>>(
        WhX, SEG_RATES, accI, WhY, SEG_FOLLOWS, accU, row_start, csr_src);
    gemm2<<<gb2, 256, 0, stream>>>(emb_item, wf_similar, wf_rated_by, b1_similar, b1_rated_by,
                                   WhX, WhY, N_ITEM);
    pull128_pair<true><<<dim3(pb, 2), 256, 0, stream>>>(
        WhX, SEG_SIMILAR, accI, WhY, SEG_RATED_BY, accU, row_start, csr_src);

    // ---------------- layer 2 (user output only; lrelu fused into GEMM A-load) ----------------
    gemm1_l2_pair<<<dim3(gbl, 2), 256, 0, stream>>>(
        accI, accU, wf2_rb, wf2_f, b2_rated_by, b2_follows, WhX, WhY, N_ITEM);
    dual_pull64<<<pb, 256, 0, stream>>>(WhX, WhY, row_start, csr_src, out);
}

// Round 10
// 318.048 us; speedup vs baseline: 14.5356x; 1.0426x over previous
//
#include <hip/hip_runtime.h>
#include <hip/hip_fp16.h>

#define N_USER 100000
#define N_ITEM 100000
#define NEDGE  500000
#define NKEY   400000          // 4 relations x 100k dst nodes
#define BSHIFT 11              // 2048 keys per bucket
#define NB     196             // ceil(NKEY / 2048)
#define BCAP   11264           // pairs per bucket (mean 10240 -> +10 sigma)
#define TILE   4096

#define SEG_RATES    0
#define SEG_RATED_BY 100000
#define SEG_FOLLOWS  200000
#define SEG_SIMILAR  300000

typedef _Float16 f16x8 __attribute__((ext_vector_type(8)));
typedef float    f32x4 __attribute__((ext_vector_type(4)));

// ---------------- weight pre-shuffle (all 6 matrices) + bucket_cursor zeroing ----------------
// dst chunk=(n>>4)*4+(k>>5), lane=((k>>3)&3)*16+(n&15), e=k&7
__global__ void prep_w_all(const float* __restrict__ W0, const float* __restrict__ W1,
                           const float* __restrict__ W2, const float* __restrict__ W3,
                           const float* __restrict__ W4, const float* __restrict__ W5,
                           __half* __restrict__ D0, __half* __restrict__ D1,
                           __half* __restrict__ D2, __half* __restrict__ D3,
                           __half* __restrict__ D4, __half* __restrict__ D5,
                           int* __restrict__ bucket_cursor)
{
    int y = blockIdx.y;
    if (y == 0 && blockIdx.x == 0 && threadIdx.x < NB)
        bucket_cursor[threadIdx.x] = 0;
    const float* W = y == 0 ? W0 : y == 1 ? W1 : y == 2 ? W2 : y == 3 ? W3 : y == 4 ? W4 : W5;
    __half* dst    = y == 0 ? D0 : y == 1 ? D1 : y == 2 ? D2 : y == 3 ? D3 : y == 4 ? D4 : D5;
    int N = y < 4 ? 128 : 64;
    int i = blockIdx.x * 256 + threadIdx.x;
    if (i >= 128 * N) return;
    int k = i / N, n = i % N;
    int chunk = (n >> 4) * 4 + (k >> 5);
    int lane  = ((k >> 3) & 3) * 16 + (n & 15);
    int e     = k & 7;
    dst[(chunk * 64 + lane) * 8 + e] = __float2half(W[i]);
}

// ---------------- dual-output MFMA GEMM, 64-row blocks, A fully preloaded ----------------
__global__ __launch_bounds__(256, 3)
void gemm2(const float* __restrict__ A,
           const __half* __restrict__ Wf0, const __half* __restrict__ Wf1,
           const float* __restrict__ b0, const float* __restrict__ b1,
           __half* __restrict__ out0, __half* __restrict__ out1, int M)
{
    const int tid = threadIdx.x;
    const int wave = tid >> 6, lane = tid & 63;
    const int l16 = lane & 15, lk = lane >> 4;
    const int rowBase = blockIdx.x * 64 + wave * 16;

    f32x4 acc0[8], acc1[8];
#pragma unroll
    for (int n = 0; n < 8; ++n) { acc0[n] = (f32x4)0.f; acc1[n] = (f32x4)0.f; }

    const int gr = rowBase + l16;
    const bool valid = gr < M;
    const float* ap = A + (size_t)(valid ? gr : 0) * 128 + lk * 8;
    float4 av[8];
#pragma unroll
    for (int kt = 0; kt < 4; ++kt) {
        av[2 * kt]     = *reinterpret_cast<const float4*>(ap + kt * 32);
        av[2 * kt + 1] = *reinterpret_cast<const float4*>(ap + kt * 32 + 4);
    }
    if (!valid) {
#pragma unroll
        for (int j = 0; j < 8; ++j) av[j] = make_float4(0.f, 0.f, 0.f, 0.f);
    }

#pragma unroll
    for (int kt = 0; kt < 4; ++kt) {
        f16x8 af;
        af[0] = (_Float16)av[2 * kt].x;     af[1] = (_Float16)av[2 * kt].y;
        af[2] = (_Float16)av[2 * kt].z;     af[3] = (_Float16)av[2 * kt].w;
        af[4] = (_Float16)av[2 * kt + 1].x; af[5] = (_Float16)av[2 * kt + 1].y;
        af[6] = (_Float16)av[2 * kt + 1].z; af[7] = (_Float16)av[2 * kt + 1].w;
#pragma unroll
        for (int n = 0; n < 8; ++n) {
            const size_t cidx = (size_t)((n * 4 + kt) * 64 + lane) * 8;
            f16x8 bf0 = *reinterpret_cast<const f16x8*>(Wf0 + cidx);
            f16x8 bf1 = *reinterpret_cast<const f16x8*>(Wf1 + cidx);
            acc0[n] = __builtin_amdgcn_mfma_f32_16x16x32_f16(af, bf0, acc0[n], 0, 0, 0);
            acc1[n] = __builtin_amdgcn_mfma_f32_16x16x32_f16(af, bf1, acc1[n], 0, 0, 0);
        }
    }

    const int gr0 = rowBase + lk * 4;
#pragma unroll
    for (int n = 0; n < 8; ++n) {
        float bv0 = b0[n * 16 + l16];
        float bv1 = b1[n * 16 + l16];
#pragma unroll
        for (int r = 0; r < 4; ++r) {
            int grr = gr0 + r;
            if (grr < M) {
                out0[(size_t)grr * 128 + n * 16 + l16] = __float2half(acc0[n][r] + bv0);
                out1[(size_t)grr * 128 + n * 16 + l16] = __float2half(acc1[n][r] + bv1);
            }
        }
    }
}

// ---------------- fused pair of layer-2 GEMMs: out[M][64] = lrelu(A fp16) @ W + b ----------------
__global__ __launch_bounds__(256, 4)
void gemm1_l2_pair(const __half* __restrict__ A0, const __half* __restrict__ A1,
                   const __half* __restrict__ Wf0, const __half* __restrict__ Wf1,
                   const float* __restrict__ bias0, const float* __restrict__ bias1,
                   __half* __restrict__ O0, __half* __restrict__ O1, int M)
{
    const __half* A  = blockIdx.y ? A1 : A0;
    const __half* Wf = blockIdx.y ? Wf1 : Wf0;
    const float* bias = blockIdx.y ? bias1 : bias0;
    __half* out = blockIdx.y ? O1 : O0;

    const int tid = threadIdx.x;
    const int wave = tid >> 6, lane = tid & 63;
    const int l16 = lane & 15, lk = lane >> 4;
    const int rowBase = blockIdx.x * 128 + wave * 32;

    f32x4 acc[2][4];
#pragma unroll
    for (int m = 0; m < 2; ++m)
#pragma unroll
        for (int n = 0; n < 4; ++n) acc[m][n] = (f32x4)0.f;

#pragma unroll
    for (int kt = 0; kt < 4; ++kt) {
        f16x8 af[2];
#pragma unroll
        for (int m = 0; m < 2; ++m) {
            int gr = rowBase + m * 16 + l16;
            f16x8 a = (f16x8)(_Float16)0.f;
            if (gr < M)
                a = *reinterpret_cast<const f16x8*>(&A[(size_t)gr * 128 + kt * 32 + lk * 8]);
#pragma unroll
            for (int e = 0; e < 8; ++e) {
                float x = (float)a[e];
                x = x > 0.f ? x : 0.01f * x;
                a[e] = (_Float16)x;
            }
            af[m] = a;
        }
#pragma unroll
        for (int n = 0; n < 4; ++n) {
            const size_t cidx = (size_t)((n * 4 + kt) * 64 + lane) * 8;
            f16x8 bf = *reinterpret_cast<const f16x8*>(Wf + cidx);
            acc[0][n] = __builtin_amdgcn_mfma_f32_16x16x32_f16(af[0], bf, acc[0][n], 0, 0, 0);
            acc[1][n] = __builtin_amdgcn_mfma_f32_16x16x32_f16(af[1], bf, acc[1][n], 0, 0, 0);
        }
    }

#pragma unroll
    for (int m = 0; m < 2; ++m) {
        int gr0 = rowBase + m * 16 + lk * 4;
#pragma unroll
        for (int n = 0; n < 4; ++n) {
            float bv = bias[n * 16 + l16];
#pragma unroll
            for (int r = 0; r < 4; ++r) {
                int gr = gr0 + r;
                if (gr < M)
                    out[(size_t)gr * 64 + n * 16 + l16] = __float2half(acc[m][n][r] + bv);
            }
        }
    }
}

// ---------------- pass 1: partition edges into 196 buckets of (key,src) pairs ----------------
__global__ __launch_bounds__(256)
void partition_kernel(const int* __restrict__ s0, const int* __restrict__ d0,
                      const int* __restrict__ s1, const int* __restrict__ d1,
                      const int* __restrict__ s2, const int* __restrict__ d2,
                      const int* __restrict__ s3, const int* __restrict__ d3,
                      int* __restrict__ bucket_cursor, uint2* __restrict__ pairbuf)
{
    __shared__ int cntS[256], lscan[256], gbase[256], cur[256];
    __shared__ uint2 stage[TILE];
    __shared__ unsigned char bslot[TILE];

    const int t = threadIdx.x;
    const int rel = blockIdx.y;
    const int* S = rel == 0 ? s0 : rel == 1 ? s1 : rel == 2 ? s2 : s3;
    const int* D = rel == 0 ? d0 : rel == 1 ? d1 : rel == 2 ? d2 : d3;
    const int tileBase = blockIdx.x * TILE;
    const int tileN = min(TILE, NEDGE - tileBase);

    cntS[t] = 0;
    __syncthreads();

    int key[16], sv[16];
#pragma unroll
    for (int k = 0; k < 16; ++k) {
        int i = tileBase + k * 256 + t;
        if (i < NEDGE) {
            sv[k]  = S[i];
            key[k] = rel * 100000 + D[i];
            atomicAdd(&cntS[key[k] >> BSHIFT], 1);
        } else key[k] = -1;
    }
    __syncthreads();

    const int c = cntS[t];
    lscan[t] = c;
    __syncthreads();
    for (int off = 1; off < 256; off <<= 1) {
        int v = (t >= off) ? lscan[t - off] : 0;
        __syncthreads();
        lscan[t] += v;
        __syncthreads();
    }
    const int ex = lscan[t] - c;
    __syncthreads();
    lscan[t] = ex;
    cur[t]   = ex;
    if (t < NB && c > 0) gbase[t] = atomicAdd(&bucket_cursor[t], c);
    __syncthreads();

#pragma unroll
    for (int k = 0; k < 16; ++k) {
        if (key[k] >= 0) {
            int b = key[k] >> BSHIFT;
            int slot = atomicAdd(&cur[b], 1);
            stage[slot] = make_uint2((unsigned)key[k], (unsigned)sv[k]);
            bslot[slot] = (unsigned char)b;
        }
    }
    __syncthreads();

    for (int j = t; j < tileN; j += 256) {
        int b = bslot[j];
        pairbuf[(size_t)b * BCAP + gbase[b] + (j - lscan[b])] = stage[j];
    }
}

// ---------------- pass 2: per-bucket bin sort -> row_start + csr_src (self-prefix) ----------------
__global__ __launch_bounds__(256)
void build_csr(const uint2* __restrict__ pairbuf, const int* __restrict__ bucket_cursor,
               int* __restrict__ row_start, int* __restrict__ csr_src)
{
    __shared__ int hist[2048];
    __shared__ int scan2[2048];
    __shared__ int partial[256];
    __shared__ int red[256];

    const int b = blockIdx.x;
    const int t = threadIdx.x;

    // prefix over buckets < b (256-thread tree reduce)
    red[t] = (t < b) ? bucket_cursor[t] : 0;
    __syncthreads();
    for (int off = 128; off > 0; off >>= 1) {
        if (t < off) red[t] += red[t + off];
        __syncthreads();
    }
    const int gs = red[0];
    const int cnt = bucket_cursor[b];
    const uint2* pb = pairbuf + (size_t)b * BCAP;
    const int keyBase = b << BSHIFT;
    const int nbin = min(2048, NKEY - keyBase);

    for (int k = t; k < 2048; k += 256) hist[k] = 0;
    __syncthreads();
    for (int j = t; j < cnt; j += 256)
        atomicAdd(&hist[(int)pb[j].x - keyBase], 1);
    __syncthreads();

    const int base8 = t * 8;
    int s = 0;
#pragma unroll
    for (int k = 0; k < 8; ++k) s += hist[base8 + k];
    partial[t] = s;
    __syncthreads();
    for (int off = 1; off < 256; off <<= 1) {
        int u = (t >= off) ? partial[t - off] : 0;
        __syncthreads();
        partial[t] += u;
        __syncthreads();
    }
    int run = partial[t] - s;
#pragma unroll
    for (int k = 0; k < 8; ++k) { scan2[base8 + k] = run; run += hist[base8 + k]; }
    __syncthreads();

    for (int k = t; k < nbin; k += 256) row_start[keyBase + k] = gs + scan2[k];
    for (int k = t; k < 2048; k += 256) hist[k] = scan2[k];
    if (b == NB - 1 && t == 0) row_start[NKEY] = 4 * NEDGE;
    __syncthreads();

    for (int j = t; j < cnt; j += 256) {
        uint2 p = pb[j];
        int pos = atomicAdd(&hist[(int)p.x - keyBase], 1);
        csr_src[gs + pos] = (int)p.y;
    }
}

// ---------------- fused pair of 128-wide pulls; 16-lane groups, 2-deep edge unroll ------
template<bool ACCUM>
__global__ __launch_bounds__(256)
void pull128_pair(const __half* __restrict__ WhA, int segA, __half* __restrict__ outA,
                  const __half* __restrict__ WhB, int segB, __half* __restrict__ outB,
                  const int* __restrict__ row_start, const int* __restrict__ csr_src)
{
    const __half* Wh = blockIdx.y ? WhB : WhA;
    __half* out      = blockIdx.y ? outB : outA;
    const int seg    = blockIdx.y ? segB : segA;

    const int wid = (blockIdx.x * 256 + threadIdx.x) >> 6;
    if (wid >= 100000) return;
    const int g  = (threadIdx.x >> 4) & 3;
    const int sl = threadIdx.x & 15;
    const int idx = seg + wid;
    const int s0 = row_start[idx], s1 = row_start[idx + 1];
    const float inv = 1.0f / (float)max(s1 - s0, 1);

    float acc[8];
#pragma unroll
    for (int j = 0; j < 8; ++j) acc[j] = 0.f;

    int e = s0 + g;
    // 2 edges in flight per group
    for (; e + 4 < s1; e += 8) {
        int i1 = csr_src[e];
        int i2 = csr_src[e + 4];
        uint4 u1 = *reinterpret_cast<const uint4*>(&Wh[(size_t)i1 * 128 + sl * 8]);
        uint4 u2 = *reinterpret_cast<const uint4*>(&Wh[(size_t)i2 * 128 + sl * 8]);
        const __half2* h1 = reinterpret_cast<const __half2*>(&u1);
        const __half2* h2 = reinterpret_cast<const __half2*>(&u2);
#pragma unroll
        for (int j = 0; j < 4; ++j) {
            float2 f1 = __half22float2(h1[j]);
            float2 f2 = __half22float2(h2[j]);
            acc[2 * j] += f1.x + f2.x; acc[2 * j + 1] += f1.y + f2.y;
        }
    }
    if (e < s1) {
        int i1 = csr_src[e];
        uint4 u1 = *reinterpret_cast<const uint4*>(&Wh[(size_t)i1 * 128 + sl * 8]);
        const __half2* h1 = reinterpret_cast<const __half2*>(&u1);
#pragma unroll
        for (int j = 0; j < 4; ++j) {
            float2 f1 = __half22float2(h1[j]);
            acc[2 * j] += f1.x; acc[2 * j + 1] += f1.y;
        }
    }
#pragma unroll
    for (int j = 0; j < 8; ++j) {
        acc[j] += __shfl_xor(acc[j], 16);
        acc[j] += __shfl_xor(acc[j], 32);
        acc[j] *= inv;
    }
    if (g == 0) {
        __half* o = out + (size_t)wid * 128 + sl * 8;
        if (ACCUM) {
            uint4 c = *reinterpret_cast<const uint4*>(o);
            const __half2* cp = reinterpret_cast<const __half2*>(&c);
#pragma unroll
            for (int j = 0; j < 4; ++j) {
                float2 f = __half22float2(cp[j]);
                acc[2 * j] += f.x; acc[2 * j + 1] += f.y;
            }
        }
        uint4 st;
        __half2* sp = reinterpret_cast<__half2*>(&st);
#pragma unroll
        for (int j = 0; j < 4; ++j) sp[j] = __floats2half2_rn(acc[2 * j], acc[2 * j + 1]);
        *reinterpret_cast<uint4*>(o) = st;
    }
}

// ---------------- final dual-segment pull: out = mean_rb(WhRB) + mean_f(WhF), fp32 ------
// groups 0,1 -> rated_by ; groups 2,3 -> follows ; 2-deep edge unroll
__global__ __launch_bounds__(256)
void dual_pull64(const __half* __restrict__ WhRB, const __half* __restrict__ WhF,
                 const int* __restrict__ row_start, const int* __restrict__ csr_src,
                 float* __restrict__ out)
{
    const int wid = (blockIdx.x * 256 + threadIdx.x) >> 6;
    if (wid >= N_USER) return;
    const int g  = (threadIdx.x >> 4) & 3;
    const int sl = threadIdx.x & 15;

    const int rb0 = row_start[SEG_RATED_BY + wid], rb1 = row_start[SEG_RATED_BY + wid + 1];
    const int f0  = row_start[SEG_FOLLOWS  + wid], f1  = row_start[SEG_FOLLOWS  + wid + 1];
    const float invRB = 1.0f / (float)max(rb1 - rb0, 1);
    const float invF  = 1.0f / (float)max(f1 - f0, 1);

    const __half* Wh = (g < 2) ? WhRB : WhF;
    int e       = (g < 2) ? rb0 + (g & 1) : f0 + (g & 1);
    const int e1 = (g < 2) ? rb1 : f1;

    float acc[4] = {0.f, 0.f, 0.f, 0.f};
    for (; e + 2 < e1; e += 4) {
        int i1 = csr_src[e];
        int i2 = csr_src[e + 2];
        uint2 u1 = *reinterpret_cast<const uint2*>(&Wh[(size_t)i1 * 64 + sl * 4]);
        uint2 u2 = *reinterpret_cast<const uint2*>(&Wh[(size_t)i2 * 64 + sl * 4]);
        const __half2* h1 = reinterpret_cast<const __half2*>(&u1);
        const __half2* h2 = reinterpret_cast<const __half2*>(&u2);
        float2 a1 = __half22float2(h1[0]), b1v = __half22float2(h1[1]);
        float2 a2 = __half22float2(h2[0]), b2v = __half22float2(h2[1]);
        acc[0] += a1.x + a2.x; acc[1] += a1.y + a2.y;
        acc[2] += b1v.x + b2v.x; acc[3] += b1v.y + b2v.y;
    }
    if (e < e1) {
        int i1 = csr_src[e];
        uint2 u1 = *reinterpret_cast<const uint2*>(&Wh[(size_t)i1 * 64 + sl * 4]);
        const __half2* h1 = reinterpret_cast<const __half2*>(&u1);
        float2 a1 = __half22float2(h1[0]), b1v = __half22float2(h1[1]);
        acc[0] += a1.x; acc[1] += a1.y; acc[2] += b1v.x; acc[3] += b1v.y;
    }
    const float sc = (g < 2) ? invRB : invF;
#pragma unroll
    for (int j = 0; j < 4; ++j) {
        acc[j] += __shfl_xor(acc[j], 16);   // combine the 2 groups of the same segment
        acc[j] *= sc;                       // per-segment mean
        acc[j] += __shfl_xor(acc[j], 32);   // rb + f
    }
    if (g == 0) {
        float4 v = make_float4(acc[0], acc[1], acc[2], acc[3]);
        *reinterpret_cast<float4*>(&out[(size_t)wid * 64 + sl * 4]) = v;
    }
}

extern "C" void kernel_launch(void* const* d_in, const int* in_sizes, int n_in,
                              void* d_out, int out_size, void* d_ws, size_t ws_size,
                              hipStream_t stream)
{
    const float* emb_user = (const float*)d_in[0];
    const float* emb_item = (const float*)d_in[1];
    const float* W1_rates    = (const float*)d_in[2];
    const float* b1_rates    = (const float*)d_in[3];
    const float* W1_rated_by = (const float*)d_in[6];
    const float* b1_rated_by = (const float*)d_in[7];
    const float* W2_rated_by = (const float*)d_in[8];
    const float* b2_rated_by = (const float*)d_in[9];
    const float* W1_follows  = (const float*)d_in[10];
    const float* b1_follows  = (const float*)d_in[11];
    const float* W2_follows  = (const float*)d_in[12];
    const float* b2_follows  = (const float*)d_in[13];
    const float* W1_similar  = (const float*)d_in[14];
    const float* b1_similar  = (const float*)d_in[15];
    const int* src_rates    = (const int*)d_in[18];
    const int* dst_rates    = (const int*)d_in[19];
    const int* src_rated_by = (const int*)d_in[20];
    const int* dst_rated_by = (const int*)d_in[21];
    const int* src_follows  = (const int*)d_in[22];
    const int* dst_follows  = (const int*)d_in[23];
    const int* src_similar  = (const int*)d_in[24];
    const int* dst_similar  = (const int*)d_in[25];

    float* out = (float*)d_out;

    // ---- workspace layout (bytes) ----
    char* base = (char*)d_ws;
    __half* WhX  = (__half*)base;                       // 25.6MB (pairbuf aliases during CSR build)
    __half* WhY  = (__half*)(base + 25600000);
    __half* accI = (__half*)(base + 51200000);
    __half* accU = (__half*)(base + 76800000);
    int* csr_src   = (int*)(base + 102400000);
    int* row_start = (int*)(base + 110400000);
    int* bucket_cursor = (int*)(base + 112000016);
    __half* wf = (__half*)(base + 112002080);
    __half* wf_rates    = wf;
    __half* wf_follows  = wf + 16384;
    __half* wf_similar  = wf + 32768;
    __half* wf_rated_by = wf + 49152;
    __half* wf2_rb      = wf + 65536;   // 128x64
    __half* wf2_f       = wf + 73728;
    uint2* pairbuf = (uint2*)WhX;       // dead before first gemm2 writes WhX

    prep_w_all<<<dim3(64, 6), 256, 0, stream>>>(
        W1_rates, W1_follows, W1_similar, W1_rated_by, W2_rated_by, W2_follows,
        wf_rates, wf_follows, wf_similar, wf_rated_by, wf2_rb, wf2_f, bucket_cursor);

    const int tiles = (NEDGE + TILE - 1) / TILE;   // 123
    partition_kernel<<<dim3(tiles, 4), 256, 0, stream>>>(
        src_rates, dst_rates, src_rated_by, dst_rated_by,
        src_follows, dst_follows, src_similar, dst_similar,
        bucket_cursor, pairbuf);
    build_csr<<<NB, 256, 0, stream>>>(pairbuf, bucket_cursor, row_start, csr_src);

    const int gb2 = (100000 + 63) / 64;        // 1563 (gemm2, 64-row blocks)
    const int gbl = (100000 + 127) / 128;      // 782  (gemm1_l2_pair)
    const int pb  = (100000 + 3) / 4;          // 25000 (pulls: 4 waves/block, 1 row/wave)

    // ---------------- layer 1 ----------------
    gemm2<<<gb2, 256, 0, stream>>>(emb_user, wf_rates, wf_follows, b1_rates, b1_follows,
                                   WhX, WhY, N_USER);
    pull128_pair<false><<<dim3(pb, 2), 256, 0, stream>>>(
        WhX, SEG_RATES, accI, WhY, SEG_FOLLOWS, accU, row_start, csr_src);
    gemm2<<<gb2, 256, 0, stream>>>(emb_item, wf_similar, wf_rated_by, b1_similar, b1_rated_by,
                                   WhX, WhY, N_ITEM);
    pull128_pair<true><<<dim3(pb, 2), 256, 0, stream>>>(
        WhX, SEG_SIMILAR, accI, WhY, SEG_RATED_BY, accU, row_start, csr_src);

    // ---------------- layer 2 (user output only; lrelu fused into GEMM A-load) ----------------
    gemm1_l2_pair<<<dim3(gbl, 2), 256, 0, stream>>>(
        accI, accU, wf2_rb, wf2_f, b2_rated_by, b2_follows, WhX, WhY, N_ITEM);
    dual_pull64<<<pb, 256, 0, stream>>>(WhX, WhY, row_start, csr_src, out);
}

// Round 11
// 311.226 us; speedup vs baseline: 14.8542x; 1.0219x over previous
//
#include <hip/hip_runtime.h>
#include <hip/hip_fp16.h>

#define N_USER 100000
#define N_ITEM 100000
#define NEDGE  500000
#define NKEY   400000          // 4 relations x 100k dst nodes
#define BSHIFT 11              // 2048 keys per bucket
#define NB     196             // ceil(NKEY / 2048)
#define BCAP   11264           // pairs per bucket (mean 10240 -> +10 sigma)
#define TILE   4096

#define SEG_RATES    0
#define SEG_RATED_BY 100000
#define SEG_FOLLOWS  200000
#define SEG_SIMILAR  300000

typedef _Float16 f16x8 __attribute__((ext_vector_type(8)));
typedef float    f32x4 __attribute__((ext_vector_type(4)));

// ---------------- weight pre-shuffle (all 6 matrices) + bucket_cursor zeroing ----------------
__global__ void prep_w_all(const float* __restrict__ W0, const float* __restrict__ W1,
                           const float* __restrict__ W2, const float* __restrict__ W3,
                           const float* __restrict__ W4, const float* __restrict__ W5,
                           __half* __restrict__ D0, __half* __restrict__ D1,
                           __half* __restrict__ D2, __half* __restrict__ D3,
                           __half* __restrict__ D4, __half* __restrict__ D5,
                           int* __restrict__ bucket_cursor)
{
    int y = blockIdx.y;
    if (y == 0 && blockIdx.x == 0 && threadIdx.x < NB)
        bucket_cursor[threadIdx.x] = 0;
    const float* W = y == 0 ? W0 : y == 1 ? W1 : y == 2 ? W2 : y == 3 ? W3 : y == 4 ? W4 : W5;
    __half* dst    = y == 0 ? D0 : y == 1 ? D1 : y == 2 ? D2 : y == 3 ? D3 : y == 4 ? D4 : D5;
    int N = y < 4 ? 128 : 64;
    int i = blockIdx.x * 256 + threadIdx.x;
    if (i >= 128 * N) return;
    int k = i / N, n = i % N;
    int chunk = (n >> 4) * 4 + (k >> 5);
    int lane  = ((k >> 3) & 3) * 16 + (n & 15);
    int e     = k & 7;
    dst[(chunk * 64 + lane) * 8 + e] = __float2half(W[i]);
}

// ---------------- dual-output MFMA GEMM, 64-row blocks, A fully preloaded ----------------
__global__ __launch_bounds__(256, 3)
void gemm2(const float* __restrict__ A,
           const __half* __restrict__ Wf0, const __half* __restrict__ Wf1,
           const float* __restrict__ b0, const float* __restrict__ b1,
           __half* __restrict__ out0, __half* __restrict__ out1, int M)
{
    const int tid = threadIdx.x;
    const int wave = tid >> 6, lane = tid & 63;
    const int l16 = lane & 15, lk = lane >> 4;
    const int rowBase = blockIdx.x * 64 + wave * 16;

    f32x4 acc0[8], acc1[8];
#pragma unroll
    for (int n = 0; n < 8; ++n) { acc0[n] = (f32x4)0.f; acc1[n] = (f32x4)0.f; }

    const int gr = rowBase + l16;
    const bool valid = gr < M;
    const float* ap = A + (size_t)(valid ? gr : 0) * 128 + lk * 8;
    float4 av[8];
#pragma unroll
    for (int kt = 0; kt < 4; ++kt) {
        av[2 * kt]     = *reinterpret_cast<const float4*>(ap + kt * 32);
        av[2 * kt + 1] = *reinterpret_cast<const float4*>(ap + kt * 32 + 4);
    }
    if (!valid) {
#pragma unroll
        for (int j = 0; j < 8; ++j) av[j] = make_float4(0.f, 0.f, 0.f, 0.f);
    }

#pragma unroll
    for (int kt = 0; kt < 4; ++kt) {
        f16x8 af;
        af[0] = (_Float16)av[2 * kt].x;     af[1] = (_Float16)av[2 * kt].y;
        af[2] = (_Float16)av[2 * kt].z;     af[3] = (_Float16)av[2 * kt].w;
        af[4] = (_Float16)av[2 * kt + 1].x; af[5] = (_Float16)av[2 * kt + 1].y;
        af[6] = (_Float16)av[2 * kt + 1].z; af[7] = (_Float16)av[2 * kt + 1].w;
#pragma unroll
        for (int n = 0; n < 8; ++n) {
            const size_t cidx = (size_t)((n * 4 + kt) * 64 + lane) * 8;
            f16x8 bf0 = *reinterpret_cast<const f16x8*>(Wf0 + cidx);
            f16x8 bf1 = *reinterpret_cast<const f16x8*>(Wf1 + cidx);
            acc0[n] = __builtin_amdgcn_mfma_f32_16x16x32_f16(af, bf0, acc0[n], 0, 0, 0);
            acc1[n] = __builtin_amdgcn_mfma_f32_16x16x32_f16(af, bf1, acc1[n], 0, 0, 0);
        }
    }

    const int gr0 = rowBase + lk * 4;
#pragma unroll
    for (int n = 0; n < 8; ++n) {
        float bv0 = b0[n * 16 + l16];
        float bv1 = b1[n * 16 + l16];
#pragma unroll
        for (int r = 0; r < 4; ++r) {
            int grr = gr0 + r;
            if (grr < M) {
                out0[(size_t)grr * 128 + n * 16 + l16] = __float2half(acc0[n][r] + bv0);
                out1[(size_t)grr * 128 + n * 16 + l16] = __float2half(acc1[n][r] + bv1);
            }
        }
    }
}

// ---------------- fused pair of layer-2 GEMMs: out[M][64] = lrelu(A fp16) @ W + b ----------------
__global__ __launch_bounds__(256, 4)
void gemm1_l2_pair(const __half* __restrict__ A0, const __half* __restrict__ A1,
                   const __half* __restrict__ Wf0, const __half* __restrict__ Wf1,
                   const float* __restrict__ bias0, const float* __restrict__ bias1,
                   __half* __restrict__ O0, __half* __restrict__ O1, int M)
{
    const __half* A  = blockIdx.y ? A1 : A0;
    const __half* Wf = blockIdx.y ? Wf1 : Wf0;
    const float* bias = blockIdx.y ? bias1 : bias0;
    __half* out = blockIdx.y ? O1 : O0;

    const int tid = threadIdx.x;
    const int wave = tid >> 6, lane = tid & 63;
    const int l16 = lane & 15, lk = lane >> 4;
    const int rowBase = blockIdx.x * 128 + wave * 32;

    f32x4 acc[2][4];
#pragma unroll
    for (int m = 0; m < 2; ++m)
#pragma unroll
        for (int n = 0; n < 4; ++n) acc[m][n] = (f32x4)0.f;

#pragma unroll
    for (int kt = 0; kt < 4; ++kt) {
        f16x8 af[2];
#pragma unroll
        for (int m = 0; m < 2; ++m) {
            int gr = rowBase + m * 16 + l16;
            f16x8 a = (f16x8)(_Float16)0.f;
            if (gr < M)
                a = *reinterpret_cast<const f16x8*>(&A[(size_t)gr * 128 + kt * 32 + lk * 8]);
#pragma unroll
            for (int e = 0; e < 8; ++e) {
                float x = (float)a[e];
                x = x > 0.f ? x : 0.01f * x;
                a[e] = (_Float16)x;
            }
            af[m] = a;
        }
#pragma unroll
        for (int n = 0; n < 4; ++n) {
            const size_t cidx = (size_t)((n * 4 + kt) * 64 + lane) * 8;
            f16x8 bf = *reinterpret_cast<const f16x8*>(Wf + cidx);
            acc[0][n] = __builtin_amdgcn_mfma_f32_16x16x32_f16(af[0], bf, acc[0][n], 0, 0, 0);
            acc[1][n] = __builtin_amdgcn_mfma_f32_16x16x32_f16(af[1], bf, acc[1][n], 0, 0, 0);
        }
    }

#pragma unroll
    for (int m = 0; m < 2; ++m) {
        int gr0 = rowBase + m * 16 + lk * 4;
#pragma unroll
        for (int n = 0; n < 4; ++n) {
            float bv = bias[n * 16 + l16];
#pragma unroll
            for (int r = 0; r < 4; ++r) {
                int gr = gr0 + r;
                if (gr < M)
                    out[(size_t)gr * 64 + n * 16 + l16] = __float2half(acc[m][n][r] + bv);
            }
        }
    }
}

// ---------------- pass 1: partition edges into 196 buckets of (key,src) pairs ----------------
__global__ __launch_bounds__(256)
void partition_kernel(const int* __restrict__ s0, const int* __restrict__ d0,
                      const int* __restrict__ s1, const int* __restrict__ d1,
                      const int* __restrict__ s2, const int* __restrict__ d2,
                      const int* __restrict__ s3, const int* __restrict__ d3,
                      int* __restrict__ bucket_cursor, uint2* __restrict__ pairbuf)
{
    __shared__ int cntS[256], lscan[256], gbase[256], cur[256];
    __shared__ uint2 stage[TILE];
    __shared__ unsigned char bslot[TILE];

    const int t = threadIdx.x;
    const int rel = blockIdx.y;
    const int* S = rel == 0 ? s0 : rel == 1 ? s1 : rel == 2 ? s2 : s3;
    const int* D = rel == 0 ? d0 : rel == 1 ? d1 : rel == 2 ? d2 : d3;
    const int tileBase = blockIdx.x * TILE;
    const int tileN = min(TILE, NEDGE - tileBase);

    cntS[t] = 0;
    __syncthreads();

    int key[16], sv[16];
    if (tileBase + TILE <= NEDGE) {
        // full tile: vectorized int4 loads (thread t owns edges tileBase+16t .. +15)
#pragma unroll
        for (int q = 0; q < 4; ++q) {
            int4 s4 = *reinterpret_cast<const int4*>(&S[tileBase + t * 16 + q * 4]);
            int4 d4 = *reinterpret_cast<const int4*>(&D[tileBase + t * 16 + q * 4]);
            sv[q * 4 + 0] = s4.x; key[q * 4 + 0] = rel * 100000 + d4.x;
            sv[q * 4 + 1] = s4.y; key[q * 4 + 1] = rel * 100000 + d4.y;
            sv[q * 4 + 2] = s4.z; key[q * 4 + 2] = rel * 100000 + d4.z;
            sv[q * 4 + 3] = s4.w; key[q * 4 + 3] = rel * 100000 + d4.w;
        }
#pragma unroll
        for (int k = 0; k < 16; ++k)
            atomicAdd(&cntS[key[k] >> BSHIFT], 1);
    } else {
#pragma unroll
        for (int k = 0; k < 16; ++k) {
            int i = tileBase + t * 16 + k;
            if (t * 16 + k < tileN) {
                sv[k]  = S[i];
                key[k] = rel * 100000 + D[i];
                atomicAdd(&cntS[key[k] >> BSHIFT], 1);
            } else key[k] = -1;
        }
    }
    __syncthreads();

    const int c = cntS[t];
    lscan[t] = c;
    __syncthreads();
    for (int off = 1; off < 256; off <<= 1) {
        int v = (t >= off) ? lscan[t - off] : 0;
        __syncthreads();
        lscan[t] += v;
        __syncthreads();
    }
    const int ex = lscan[t] - c;
    __syncthreads();
    lscan[t] = ex;
    cur[t]   = ex;
    if (t < NB && c > 0) gbase[t] = atomicAdd(&bucket_cursor[t], c);
    __syncthreads();

#pragma unroll
    for (int k = 0; k < 16; ++k) {
        if (key[k] >= 0) {
            int b = key[k] >> BSHIFT;
            int slot = atomicAdd(&cur[b], 1);
            stage[slot] = make_uint2((unsigned)key[k], (unsigned)sv[k]);
            bslot[slot] = (unsigned char)b;
        }
    }
    __syncthreads();

    for (int j = t; j < tileN; j += 256) {
        int b = bslot[j];
        pairbuf[(size_t)b * BCAP + gbase[b] + (j - lscan[b])] = stage[j];
    }
}

// ---------------- pass 2: per-bucket bin sort -> row_start + csr_src (self-prefix) ----------------
__global__ __launch_bounds__(256)
void build_csr(const uint2* __restrict__ pairbuf, const int* __restrict__ bucket_cursor,
               int* __restrict__ row_start, int* __restrict__ csr_src)
{
    __shared__ int hist[2048];
    __shared__ int scan2[2048];
    __shared__ int partial[256];
    __shared__ int red[256];

    const int b = blockIdx.x;
    const int t = threadIdx.x;

    red[t] = (t < b) ? bucket_cursor[t] : 0;
    __syncthreads();
    for (int off = 128; off > 0; off >>= 1) {
        if (t < off) red[t] += red[t + off];
        __syncthreads();
    }
    const int gs = red[0];
    const int cnt = bucket_cursor[b];
    const uint2* pb = pairbuf + (size_t)b * BCAP;
    const int keyBase = b << BSHIFT;
    const int nbin = min(2048, NKEY - keyBase);

    for (int k = t; k < 2048; k += 256) hist[k] = 0;
    __syncthreads();
    for (int j = t; j < cnt; j += 256)
        atomicAdd(&hist[(int)pb[j].x - keyBase], 1);
    __syncthreads();

    const int base8 = t * 8;
    int s = 0;
#pragma unroll
    for (int k = 0; k < 8; ++k) s += hist[base8 + k];
    partial[t] = s;
    __syncthreads();
    for (int off = 1; off < 256; off <<= 1) {
        int u = (t >= off) ? partial[t - off] : 0;
        __syncthreads();
        partial[t] += u;
        __syncthreads();
    }
    int run = partial[t] - s;
#pragma unroll
    for (int k = 0; k < 8; ++k) { scan2[base8 + k] = run; run += hist[base8 + k]; }
    __syncthreads();

    for (int k = t; k < nbin; k += 256) row_start[keyBase + k] = gs + scan2[k];
    for (int k = t; k < 2048; k += 256) hist[k] = scan2[k];
    if (b == NB - 1 && t == 0) row_start[NKEY] = 4 * NEDGE;
    __syncthreads();

    for (int j = t; j < cnt; j += 256) {
        uint2 p = pb[j];
        int pos = atomicAdd(&hist[(int)p.x - keyBase], 1);
        csr_src[gs + pos] = (int)p.y;
    }
}

// ---------------- fused pair of 128-wide pulls; 16-lane groups, 2-deep unroll, pk_f16 acc ----
template<bool ACCUM>
__global__ __launch_bounds__(256)
void pull128_pair(const __half* __restrict__ WhA, int segA, __half* __restrict__ outA,
                  const __half* __restrict__ WhB, int segB, __half* __restrict__ outB,
                  const int* __restrict__ row_start, const int* __restrict__ csr_src)
{
    const __half* Wh = blockIdx.y ? WhB : WhA;
    __half* out      = blockIdx.y ? outB : outA;
    const int seg    = blockIdx.y ? segB : segA;

    const int wid = (blockIdx.x * 256 + threadIdx.x) >> 6;
    if (wid >= 100000) return;
    const int g  = (threadIdx.x >> 4) & 3;
    const int sl = threadIdx.x & 15;
    const int idx = seg + wid;
    const int s0 = row_start[idx], s1 = row_start[idx + 1];
    const float inv = 1.0f / (float)max(s1 - s0, 1);

    __half2 hacc[4];
#pragma unroll
    for (int j = 0; j < 4; ++j) hacc[j] = __floats2half2_rn(0.f, 0.f);

    int e = s0 + g;
    for (; e + 4 < s1; e += 8) {
        int i1 = csr_src[e];
        int i2 = csr_src[e + 4];
        uint4 u1 = *reinterpret_cast<const uint4*>(&Wh[(size_t)i1 * 128 + sl * 8]);
        uint4 u2 = *reinterpret_cast<const uint4*>(&Wh[(size_t)i2 * 128 + sl * 8]);
        const __half2* h1 = reinterpret_cast<const __half2*>(&u1);
        const __half2* h2 = reinterpret_cast<const __half2*>(&u2);
#pragma unroll
        for (int j = 0; j < 4; ++j)
            hacc[j] = __hadd2(hacc[j], __hadd2(h1[j], h2[j]));
    }
    if (e < s1) {
        int i1 = csr_src[e];
        uint4 u1 = *reinterpret_cast<const uint4*>(&Wh[(size_t)i1 * 128 + sl * 8]);
        const __half2* h1 = reinterpret_cast<const __half2*>(&u1);
#pragma unroll
        for (int j = 0; j < 4; ++j)
            hacc[j] = __hadd2(hacc[j], h1[j]);
    }

    float acc[8];
#pragma unroll
    for (int j = 0; j < 4; ++j) {
        float2 f = __half22float2(hacc[j]);
        acc[2 * j] = f.x; acc[2 * j + 1] = f.y;
    }
#pragma unroll
    for (int j = 0; j < 8; ++j) {
        acc[j] += __shfl_xor(acc[j], 16);
        acc[j] += __shfl_xor(acc[j], 32);
        acc[j] *= inv;
    }
    if (g == 0) {
        __half* o = out + (size_t)wid * 128 + sl * 8;
        if (ACCUM) {
            uint4 c = *reinterpret_cast<const uint4*>(o);
            const __half2* cp = reinterpret_cast<const __half2*>(&c);
#pragma unroll
            for (int j = 0; j < 4; ++j) {
                float2 f = __half22float2(cp[j]);
                acc[2 * j] += f.x; acc[2 * j + 1] += f.y;
            }
        }
        uint4 st;
        __half2* sp = reinterpret_cast<__half2*>(&st);
#pragma unroll
        for (int j = 0; j < 4; ++j) sp[j] = __floats2half2_rn(acc[2 * j], acc[2 * j + 1]);
        *reinterpret_cast<uint4*>(o) = st;
    }
}

// ---------------- final dual-segment pull: out = mean_rb(WhRB) + mean_f(WhF), fp32 ------
__global__ __launch_bounds__(256)
void dual_pull64(const __half* __restrict__ WhRB, const __half* __restrict__ WhF,
                 const int* __restrict__ row_start, const int* __restrict__ csr_src,
                 float* __restrict__ out)
{
    const int wid = (blockIdx.x * 256 + threadIdx.x) >> 6;
    if (wid >= N_USER) return;
    const int g  = (threadIdx.x >> 4) & 3;
    const int sl = threadIdx.x & 15;

    const int rb0 = row_start[SEG_RATED_BY + wid], rb1 = row_start[SEG_RATED_BY + wid + 1];
    const int f0  = row_start[SEG_FOLLOWS  + wid], f1  = row_start[SEG_FOLLOWS  + wid + 1];
    const float invRB = 1.0f / (float)max(rb1 - rb0, 1);
    const float invF  = 1.0f / (float)max(f1 - f0, 1);

    const __half* Wh = (g < 2) ? WhRB : WhF;
    int e        = (g < 2) ? rb0 + (g & 1) : f0 + (g & 1);
    const int e1 = (g < 2) ? rb1 : f1;

    __half2 hacc[2];
    hacc[0] = __floats2half2_rn(0.f, 0.f);
    hacc[1] = __floats2half2_rn(0.f, 0.f);
    for (; e + 2 < e1; e += 4) {
        int i1 = csr_src[e];
        int i2 = csr_src[e + 2];
        uint2 u1 = *reinterpret_cast<const uint2*>(&Wh[(size_t)i1 * 64 + sl * 4]);
        uint2 u2 = *reinterpret_cast<const uint2*>(&Wh[(size_t)i2 * 64 + sl * 4]);
        const __half2* h1 = reinterpret_cast<const __half2*>(&u1);
        const __half2* h2 = reinterpret_cast<const __half2*>(&u2);
        hacc[0] = __hadd2(hacc[0], __hadd2(h1[0], h2[0]));
        hacc[1] = __hadd2(hacc[1], __hadd2(h1[1], h2[1]));
    }
    if (e < e1) {
        int i1 = csr_src[e];
        uint2 u1 = *reinterpret_cast<const uint2*>(&Wh[(size_t)i1 * 64 + sl * 4]);
        const __half2* h1 = reinterpret_cast<const __half2*>(&u1);
        hacc[0] = __hadd2(hacc[0], h1[0]);
        hacc[1] = __hadd2(hacc[1], h1[1]);
    }

    float acc[4];
    {
        float2 fa = __half22float2(hacc[0]);
        float2 fb = __half22float2(hacc[1]);
        acc[0] = fa.x; acc[1] = fa.y; acc[2] = fb.x; acc[3] = fb.y;
    }
    const float sc = (g < 2) ? invRB : invF;
#pragma unroll
    for (int j = 0; j < 4; ++j) {
        acc[j] += __shfl_xor(acc[j], 16);   // combine the 2 groups of the same segment
        acc[j] *= sc;                       // per-segment mean
        acc[j] += __shfl_xor(acc[j], 32);   // rb + f
    }
    if (g == 0) {
        float4 v = make_float4(acc[0], acc[1], acc[2], acc[3]);
        *reinterpret_cast<float4*>(&out[(size_t)wid * 64 + sl * 4]) = v;
    }
}

extern "C" void kernel_launch(void* const* d_in, const int* in_sizes, int n_in,
                              void* d_out, int out_size, void* d_ws, size_t ws_size,
                              hipStream_t stream)
{
    const float* emb_user = (const float*)d_in[0];
    const float* emb_item = (const float*)d_in[1];
    const float* W1_rates    = (const float*)d_in[2];
    const float* b1_rates    = (const float*)d_in[3];
    const float* W1_rated_by = (const float*)d_in[6];
    const float* b1_rated_by = (const float*)d_in[7];
    const float* W2_rated_by = (const float*)d_in[8];
    const float* b2_rated_by = (const float*)d_in[9];
    const float* W1_follows  = (const float*)d_in[10];
    const float* b1_follows  = (const float*)d_in[11];
    const float* W2_follows  = (const float*)d_in[12];
    const float* b2_follows  = (const float*)d_in[13];
    const float* W1_similar  = (const float*)d_in[14];
    const float* b1_similar  = (const float*)d_in[15];
    const int* src_rates    = (const int*)d_in[18];
    const int* dst_rates    = (const int*)d_in[19];
    const int* src_rated_by = (const int*)d_in[20];
    const int* dst_rated_by = (const int*)d_in[21];
    const int* src_follows  = (const int*)d_in[22];
    const int* dst_follows  = (const int*)d_in[23];
    const int* src_similar  = (const int*)d_in[24];
    const int* dst_similar  = (const int*)d_in[25];

    float* out = (float*)d_out;

    // ---- workspace layout (bytes) ----
    char* base = (char*)d_ws;
    __half* WhX  = (__half*)base;                       // 25.6MB (pairbuf aliases during CSR build)
    __half* WhY  = (__half*)(base + 25600000);
    __half* accI = (__half*)(base + 51200000);
    __half* accU = (__half*)(base + 76800000);
    int* csr_src   = (int*)(base + 102400000);
    int* row_start = (int*)(base + 110400000);
    int* bucket_cursor = (int*)(base + 112000016);
    __half* wf = (__half*)(base + 112002080);
    __half* wf_rates    = wf;
    __half* wf_follows  = wf + 16384;
    __half* wf_similar  = wf + 32768;
    __half* wf_rated_by = wf + 49152;
    __half* wf2_rb      = wf + 65536;   // 128x64
    __half* wf2_f       = wf + 73728;
    uint2* pairbuf = (uint2*)WhX;       // dead before first gemm2 writes WhX

    prep_w_all<<<dim3(64, 6), 256, 0, stream>>>(
        W1_rates, W1_follows, W1_similar, W1_rated_by, W2_rated_by, W2_follows,
        wf_rates, wf_follows, wf_similar, wf_rated_by, wf2_rb, wf2_f, bucket_cursor);

    const int tiles = (NEDGE + TILE - 1) / TILE;   // 123
    partition_kernel<<<dim3(tiles, 4), 256, 0, stream>>>(
        src_rates, dst_rates, src_rated_by, dst_rated_by,
        src_follows, dst_follows, src_similar, dst_similar,
        bucket_cursor, pairbuf);
    build_csr<<<NB, 256, 0, stream>>>(pairbuf, bucket_cursor, row_start, csr_src);

    const int gb2 = (100000 + 63) / 64;        // 1563 (gemm2, 64-row blocks)
    const int gbl = (100000 + 127) / 128;      // 782  (gemm1_l2_pair)
    const int pb  = (100000 + 3) / 4;          // 25000 (pulls: 4 waves/block, 1 row/wave)

    // ---------------- layer 1 ----------------
    gemm2<<<gb2, 256, 0, stream>>>(emb_user, wf_rates, wf_follows, b1_rates, b1_follows,
                                   WhX, WhY, N_USER);
    pull128_pair<false><<<dim3(pb, 2), 256, 0, stream>>>(
        WhX, SEG_RATES, accI, WhY, SEG_FOLLOWS, accU, row_start, csr_src);
    gemm2<<<gb2, 256, 0, stream>>>(emb_item, wf_similar, wf_rated_by, b1_similar, b1_rated_by,
                                   WhX, WhY, N_ITEM);
    pull128_pair<true><<<dim3(pb, 2), 256, 0, stream>>>(
        WhX, SEG_SIMILAR, accI, WhY, SEG_RATED_BY, accU, row_start, csr_src);

    // ---------------- layer 2 (user output only; lrelu fused into GEMM A-load) ----------------
    gemm1_l2_pair<<<dim3(gbl, 2), 256, 0, stream>>>(
        accI, accU, wf2_rb, wf2_f, b2_rated_by, b2_follows, WhX, WhY, N_ITEM);
    dual_pull64<<<pb, 256, 0, stream>>>(WhX, WhY, row_start, csr_src, out);
}